// Round 15
// baseline (803.686 us; speedup 1.0000x reference)
//
#include <hip/hip_runtime.h>
#include <hip/hip_bf16.h>

// Problem constants (from reference)
#define NU 100000
#define NI 50000
#define NE 1000000
#define NP 500000
// D_IN = D_HID = 128, D_OUT = 64

typedef unsigned short u16;
typedef unsigned int u32;
typedef __attribute__((ext_vector_type(8))) short short8;   // 8 bf16 (4 VGPRs)
typedef __attribute__((ext_vector_type(4))) float f32x4;

static __device__ __forceinline__ u16 f2bf(float f) {
    union { float f; u32 u; } x; x.f = f;
    u32 r = x.u + 0x7fff + ((x.u >> 16) & 1);   // round-to-nearest-even
    return (u16)(r >> 16);
}
static __device__ __forceinline__ float bf2f(u16 h) {
    union { u32 u; float f; } x; x.u = ((u32)h) << 16;
    return x.f;
}

// ============ SLICED TABLE LAYOUTS ============
// 128-dim tables: [8][N][16] u16 — dim d of node t lives at
//   (d>>4)*N*16 + t*16 + (d&15).
// Rationale (r12-r14 profiles): gathers were LLC-bound at ~2.75 TB/s because
// every XCD pulled a private copy of the whole table through its 4MB L2
// (FETCH 206MB). With dim-slicing, agg blocks pin slice = blockIdx.x&7
// (= XCD round-robin), so each XCD's gather working set is table/8
// (3.2MB users / 1.6MB items) -> L2-resident. Same bytes & instruction
// count, served at L2 speed. Work per slice identical -> balanced (fixes
// r13's node-partition failure).
// proj/agg64 tables: [16][N][8] and [8][N][8] (16B rows).

// ---------------- f32 -> bf16 sliced table conversion ----------------
__global__ __launch_bounds__(256) void cvt_kernel(const float* __restrict__ in,
                                                  u16* __restrict__ out, int N) {
    int i = blockIdx.x * 256 + threadIdx.x;     // chunk index over N*16
    if (i >= N * 16) return;
    int t = i >> 4, q = i & 15;
    float4 a = *(const float4*)&in[(size_t)t * 128 + q * 8];
    float4 b = *(const float4*)&in[(size_t)t * 128 + q * 8 + 4];
    short8 o = {(short)f2bf(a.x), (short)f2bf(a.y), (short)f2bf(a.z), (short)f2bf(a.w),
                (short)f2bf(b.x), (short)f2bf(b.y), (short)f2bf(b.z), (short)f2bf(b.w)};
    *(short8*)&out[(size_t)(q >> 1) * N * 16 + (size_t)t * 16 + (q & 1) * 8] = o;
}

// ---------------- weight transposes in one launch ----------------
// wt layout (u16): 4 x (128x256) layers 0/1 [n][k], then wt_pu (128x128) and
// wt_pi (128x128) for the layer-2 pre-projection.
__global__ void wtrans_all_kernel(const float* __restrict__ Wn01,
                                  const float* __restrict__ Ws01,
                                  const float* __restrict__ Wn2,
                                  const float* __restrict__ Ws2,
                                  u16* __restrict__ wt) {
    int x = blockIdx.x;            // 0..767
    int k = threadIdx.x;           // 0..127
    if (x < 512) {
        int m = x >> 7, n = x & 127;
        const float* Wn = Wn01 + m * 16384;
        const float* Ws = Ws01 + m * 16384;
        size_t o = (size_t)m * 128 * 256;
        wt[o + (size_t)n * 256 + k]       = f2bf(Wn[(size_t)k * 128 + n]);
        wt[o + (size_t)n * 256 + 128 + k] = f2bf(Ws[(size_t)k * 128 + n]);
    } else {
        int m = (x - 512) >> 7;    // 0 = pu, 1 = pi
        int n = (x - 512) & 127;
        size_t o = 131072 + (size_t)m * 16384;
        float v;
        if (m == 0) v = (n < 64) ? Wn2[(size_t)k * 64 + n]
                                 : Ws2[8192 + (size_t)k * 64 + (n - 64)];
        else        v = (n < 64) ? Wn2[8192 + (size_t)k * 64 + n]
                                 : Ws2[(size_t)k * 64 + (n - 64)];
        wt[o + (size_t)n * 128 + k] = f2bf(v);
    }
}

// ---------------- CSR build (unchanged from r14) ----------------

__global__ void hist2_kernel(const int* __restrict__ d0, int* __restrict__ deg0,
                             int* __restrict__ rank0,
                             const int* __restrict__ d1, int* __restrict__ deg1,
                             int* __restrict__ rank1, int E) {
    int e = blockIdx.x * blockDim.x + threadIdx.x;
    if (e >= E) return;
    if (blockIdx.y == 0) {
        int d = __builtin_nontemporal_load(&d0[e]);
        int r = atomicAdd(&deg0[d], 1);
        __builtin_nontemporal_store(r, &rank0[e]);
    } else {
        int d = __builtin_nontemporal_load(&d1[e]);
        int r = atomicAdd(&deg1[d], 1);
        __builtin_nontemporal_store(r, &rank1[e]);
    }
}

__global__ void scan2_local_kernel(const int* __restrict__ in0, int* __restrict__ out0,
                                   int* __restrict__ bsum0, int n0,
                                   const int* __restrict__ in1, int* __restrict__ out1,
                                   int* __restrict__ bsum1, int n1) {
    const int* in; int *out, *bsum; int n;
    if (blockIdx.y == 0) { in = in0; out = out0; bsum = bsum0; n = n0; }
    else                 { in = in1; out = out1; bsum = bsum1; n = n1; }
    __shared__ int s[1024];
    int i = blockIdx.x * 1024 + threadIdx.x;
    int v = (i < n) ? in[i] : 0;
    s[threadIdx.x] = v;
    __syncthreads();
    for (int off = 1; off < 1024; off <<= 1) {
        int t = (threadIdx.x >= off) ? s[threadIdx.x - off] : 0;
        __syncthreads();
        s[threadIdx.x] += t;
        __syncthreads();
    }
    if (i < n) out[i] = s[threadIdx.x] - v;   // exclusive within block
    if (threadIdx.x == 1023) bsum[blockIdx.x] = s[1023];
}

__global__ void scan2_bsum_kernel(int* b0, int nb0, int* b1, int nb1) {
    int* bsum; int nb;
    if (blockIdx.y == 0) { bsum = b0; nb = nb0; }
    else                 { bsum = b1; nb = nb1; }
    __shared__ int s[1024];
    int v = ((int)threadIdx.x < nb) ? bsum[threadIdx.x] : 0;
    s[threadIdx.x] = v;
    __syncthreads();
    for (int off = 1; off < 1024; off <<= 1) {
        int t = (threadIdx.x >= off) ? s[threadIdx.x - off] : 0;
        __syncthreads();
        s[threadIdx.x] += t;
        __syncthreads();
    }
    if ((int)threadIdx.x < nb) bsum[threadIdx.x] = s[threadIdx.x] - v;  // exclusive
}

__global__ void scan2_finalize_kernel(int* __restrict__ rs0, const int* __restrict__ b0,
                                      int n0, int* __restrict__ rs1,
                                      const int* __restrict__ b1, int n1, int E) {
    int* rs; const int* bsum; int n;
    if (blockIdx.y == 0) { rs = rs0; bsum = b0; n = n0; }
    else                 { rs = rs1; bsum = b1; n = n1; }
    int i = blockIdx.x * 1024 + threadIdx.x;
    if (i < n) rs[i] += bsum[blockIdx.x];
    if (i == 0) rs[n] = E;
}

__global__ void fill2_kernel(const int* __restrict__ s0, const int* __restrict__ d0,
                             const int* __restrict__ r0, const int* __restrict__ rs0,
                             int* __restrict__ csr0,
                             const int* __restrict__ s1, const int* __restrict__ d1,
                             const int* __restrict__ r1, const int* __restrict__ rs1,
                             int* __restrict__ csr1, int E) {
    const int *src, *dst, *rk, *rs; int* csr;
    if (blockIdx.y == 0) { src = s0; dst = d0; rk = r0; rs = rs0; csr = csr0; }
    else                 { src = s1; dst = d1; rk = r1; rs = rs1; csr = csr1; }
    int e = blockIdx.x * blockDim.x + threadIdx.x;
    if (e >= E) return;
    int d = __builtin_nontemporal_load(&dst[e]);
    int r = __builtin_nontemporal_load(&rk[e]);
    int s = __builtin_nontemporal_load(&src[e]);
    csr[rs[d] + r] = s;
}

// ---------------- mean aggregation, dim-sliced, XCD-pinned ----------------
// Block = (slice s = bx&7, node group g = bx>>3); 2 lanes per node (16B each
// = the 32B slice row), 128 nodes/block; 4-deep edge unroll = 8 outstanding
// loads per lane. Gathers hit the XCD-local L2-resident sub-table. csr NT
// (stream, don't pollute L2). Items-dir blocks dispatch first -> directions
// mostly time-separated, so each L2 holds one sub-table at a time.
__global__ __launch_bounds__(256) void agg2_kernel(
    const u16* __restrict__ hu, const u16* __restrict__ hi,   // sliced [8][N][16]
    const int* __restrict__ rs_i, const int* __restrict__ csr_i,
    u16* __restrict__ out_i,                                  // sliced [8][NI][16]
    const int* __restrict__ rs_u, const int* __restrict__ csr_u,
    u16* __restrict__ out_u) {                                // sliced [8][NU][16]
    const int MI = (NI + 127) >> 7;
    const u16* tab; const int *rs, *csr; u16* out; int T, Nsrc, t0;
    int s = blockIdx.x & 7;
    int g = blockIdx.x >> 3;
    if (g < MI) { tab = hu; rs = rs_i; csr = csr_i; out = out_i;
                  T = NI; Nsrc = NU; t0 = g * 128; }
    else        { tab = hi; rs = rs_u; csr = csr_u; out = out_u;
                  T = NU; Nsrc = NI; t0 = (g - MI) * 128; }
    const u16* __restrict__ sub = tab + (size_t)s * Nsrc * 16;
    int half = threadIdx.x & 1;
    int t = t0 + (threadIdx.x >> 1);
    if (t >= T) return;
    int e0 = rs[t], e1 = rs[t + 1];
    float acc[8] = {};
    int e = e0;
    for (; e + 3 < e1; e += 4) {
        int s0 = __builtin_nontemporal_load(&csr[e]);
        int s1 = __builtin_nontemporal_load(&csr[e + 1]);
        int s2 = __builtin_nontemporal_load(&csr[e + 2]);
        int s3 = __builtin_nontemporal_load(&csr[e + 3]);
        short8 v0 = *(const short8*)&sub[(size_t)s0 * 16 + half * 8];
        short8 v1 = *(const short8*)&sub[(size_t)s1 * 16 + half * 8];
        short8 v2 = *(const short8*)&sub[(size_t)s2 * 16 + half * 8];
        short8 v3 = *(const short8*)&sub[(size_t)s3 * 16 + half * 8];
        #pragma unroll
        for (int q = 0; q < 8; ++q)
            acc[q] += (bf2f((u16)v0[q]) + bf2f((u16)v1[q])) +
                      (bf2f((u16)v2[q]) + bf2f((u16)v3[q]));
    }
    for (; e < e1; ++e) {
        int s0 = __builtin_nontemporal_load(&csr[e]);
        short8 v0 = *(const short8*)&sub[(size_t)s0 * 16 + half * 8];
        #pragma unroll
        for (int q = 0; q < 8; ++q) acc[q] += bf2f((u16)v0[q]);
    }
    float inv = (e1 > e0) ? 1.f / (float)(e1 - e0) : 0.f;
    short8 o;
    #pragma unroll
    for (int q = 0; q < 8; ++q) o[q] = (short)f2bf(acc[q] * inv);
    *(short8*)&out[(size_t)s * T * 16 + (size_t)t * 16 + half * 8] = o;
}

// ---------------- layer-2: 64-dim agg over projected tables, sliced ----------------
// proj is [16][N][8]; neighbor part = slices 0..7. 1 lane per node (16B slice
// row), 256 nodes/block, slice = bx&7 (XCD-pinned; sub-table 1.6/0.8 MB).
// Output sliced [8][T][8].
__global__ __launch_bounds__(256) void agg64_kernel(
    const u16* __restrict__ pu, const u16* __restrict__ pi,   // [16][N][8]
    const int* __restrict__ rs_i, const int* __restrict__ csr_i,
    u16* __restrict__ out_i,
    const int* __restrict__ rs_u, const int* __restrict__ csr_u,
    u16* __restrict__ out_u) {
    const int MI = (NI + 255) >> 8;
    const u16* tab; const int *rs, *csr; u16* out; int T, Nsrc, t0;
    int s = blockIdx.x & 7;
    int g = blockIdx.x >> 3;
    if (g < MI) { tab = pu; rs = rs_i; csr = csr_i; out = out_i;
                  T = NI; Nsrc = NU; t0 = g * 256; }
    else        { tab = pi; rs = rs_u; csr = csr_u; out = out_u;
                  T = NU; Nsrc = NI; t0 = (g - MI) * 256; }
    const u16* __restrict__ sub = tab + (size_t)s * Nsrc * 8;
    int t = t0 + threadIdx.x;
    if (t >= T) return;
    int e0 = rs[t], e1 = rs[t + 1];
    float acc[8] = {};
    int e = e0;
    for (; e + 3 < e1; e += 4) {
        int s0 = __builtin_nontemporal_load(&csr[e]);
        int s1 = __builtin_nontemporal_load(&csr[e + 1]);
        int s2 = __builtin_nontemporal_load(&csr[e + 2]);
        int s3 = __builtin_nontemporal_load(&csr[e + 3]);
        short8 v0 = *(const short8*)&sub[(size_t)s0 * 8];
        short8 v1 = *(const short8*)&sub[(size_t)s1 * 8];
        short8 v2 = *(const short8*)&sub[(size_t)s2 * 8];
        short8 v3 = *(const short8*)&sub[(size_t)s3 * 8];
        #pragma unroll
        for (int q = 0; q < 8; ++q)
            acc[q] += (bf2f((u16)v0[q]) + bf2f((u16)v1[q])) +
                      (bf2f((u16)v2[q]) + bf2f((u16)v3[q]));
    }
    for (; e < e1; ++e) {
        int s0 = __builtin_nontemporal_load(&csr[e]);
        short8 v0 = *(const short8*)&sub[(size_t)s0 * 8];
        #pragma unroll
        for (int q = 0; q < 8; ++q) acc[q] += bf2f((u16)v0[q]);
    }
    float inv = (e1 > e0) ? 1.f / (float)(e1 - e0) : 0.f;
    short8 o;
    #pragma unroll
    for (int q = 0; q < 8; ++q) o[q] = (short)f2bf(acc[q] * inv);
    *(short8*)&out[(size_t)s * T * 8 + (size_t)t * 8] = o;
}

// ---------------- conv via MFMA (layers 0/1), sliced in/out ----------------
// z = [hn|hd] @ Wt^T + bn + bs; relu; row L2-norm. 4 waves, 64-row tile.
// hn/hd sliced [8][T][16]; outb sliced [8][T][16].
__global__ __launch_bounds__(256) void conv2_kernel(
    const u16* __restrict__ hn_i, const u16* __restrict__ hd_i,
    const u16* __restrict__ wt_i, const float* __restrict__ bn_i,
    const float* __restrict__ bs_i, u16* __restrict__ outb_i, int ci,
    const u16* __restrict__ hn_u, const u16* __restrict__ hd_u,
    const u16* __restrict__ wt_u, const float* __restrict__ bn_u,
    const float* __restrict__ bs_u, u16* __restrict__ outb_u)
{
    constexpr int NF   = 2;
    constexpr int FSTR = 132;
    __shared__ u16 smA[64 * 264];                  // 33792 B, reused as f32 out
    __shared__ float psum[4][64];
    __shared__ float sinv[64];
    float* smF = (float*)smA;

    const u16 *hn, *hd, *Wt; const float *bn, *bs; u16* outb; int T, t0;
    if ((int)blockIdx.x < ci) {
        hn = hn_i; hd = hd_i; Wt = wt_i; bn = bn_i; bs = bs_i;
        outb = outb_i; T = NI; t0 = blockIdx.x * 64;
    } else {
        hn = hn_u; hd = hd_u; Wt = wt_u; bn = bn_u; bs = bs_u;
        outb = outb_u; T = NU; t0 = (blockIdx.x - ci) * 64;
    }

    const int tid  = threadIdx.x;
    const int wave = tid >> 6;
    const int lane = tid & 63;
    const int lr   = lane & 15;
    const int lg   = lane >> 4;

    // stage A = [hn | hd] from sliced tables: chunk q -> slice q>>1, half q&1
    #pragma unroll
    for (int i = 0; i < 8; ++i) {
        int lin = i * 256 + tid;
        int row = lin >> 5;
        int q   = lin & 31;
        int t   = t0 + row; if (t >= T) t = T - 1;
        const u16* srcp;
        if (q < 16) srcp = &hn[(size_t)(q >> 1) * T * 16 + (size_t)t * 16 + (q & 1) * 8];
        else { int qq = q - 16;
               srcp = &hd[(size_t)(qq >> 1) * T * 16 + (size_t)t * 16 + (qq & 1) * 8]; }
        *(short8*)&smA[row * 264 + (q << 3)] = *(const short8*)srcp;
    }
    __syncthreads();

    const u16* wp[NF];
    float bias[NF];
    #pragma unroll
    for (int ni = 0; ni < NF; ++ni) {
        int col = wave * 32 + ni * 16 + lr;
        wp[ni] = Wt + (size_t)col * 256;
        bias[ni] = bn[col] + bs[col];
    }

    f32x4 acc[4][NF];
    #pragma unroll
    for (int mi = 0; mi < 4; ++mi)
        #pragma unroll
        for (int ni = 0; ni < NF; ++ni)
            acc[mi][ni] = (f32x4){0.f, 0.f, 0.f, 0.f};

    #pragma unroll
    for (int ks = 0; ks < 8; ++ks) {
        const int kb = ks * 32 + (lg << 3);
        short8 b[NF];
        #pragma unroll
        for (int ni = 0; ni < NF; ++ni) b[ni] = *(const short8*)&wp[ni][kb];
        #pragma unroll
        for (int mi = 0; mi < 4; ++mi) {
            short8 a = *(const short8*)&smA[(mi * 16 + lr) * 264 + kb];
            #pragma unroll
            for (int ni = 0; ni < NF; ++ni)
                acc[mi][ni] = __builtin_amdgcn_mfma_f32_16x16x32_bf16(a, b[ni], acc[mi][ni], 0, 0, 0);
        }
    }
    __syncthreads();

    float rsum[4][4];
    #pragma unroll
    for (int mi = 0; mi < 4; ++mi) {
        #pragma unroll
        for (int j = 0; j < 4; ++j) {
            int rowg = mi * 16 + lg * 4 + j;
            float s = 0.f;
            #pragma unroll
            for (int ni = 0; ni < NF; ++ni) {
                float z = fmaxf(acc[mi][ni][j] + bias[ni], 0.f);
                int colg = wave * 32 + ni * 16 + lr;
                smF[rowg * FSTR + colg] = z;
                s = fmaf(z, z, s);
            }
            rsum[mi][j] = s;
        }
    }
    #pragma unroll
    for (int m = 1; m < 16; m <<= 1)
        #pragma unroll
        for (int mi = 0; mi < 4; ++mi)
            #pragma unroll
            for (int j = 0; j < 4; ++j)
                rsum[mi][j] += __shfl_xor(rsum[mi][j], m);
    if (lr == 0) {
        #pragma unroll
        for (int mi = 0; mi < 4; ++mi)
            #pragma unroll
            for (int j = 0; j < 4; ++j)
                psum[wave][mi * 16 + lg * 4 + j] = rsum[mi][j];
    }
    __syncthreads();
    if (tid < 64) {
        float n2 = psum[0][tid] + psum[1][tid] + psum[2][tid] + psum[3][tid];
        sinv[tid] = 1.f / fmaxf(sqrtf(n2), 1e-12f);
    }
    __syncthreads();

    // readback + sliced store: chunk g -> slice g>>1, half g&1
    #pragma unroll
    for (int i = 0; i < 4; ++i) {
        int lin = i * 256 + tid;
        int row = lin >> 4, g = lin & 15;
        int t = t0 + row;
        if (t < T) {
            float inv = sinv[row];
            float4 z0 = *(float4*)&smF[row * FSTR + g * 8];
            float4 z1 = *(float4*)&smF[row * FSTR + g * 8 + 4];
            short8 ob = {(short)f2bf(z0.x * inv), (short)f2bf(z0.y * inv),
                         (short)f2bf(z0.z * inv), (short)f2bf(z0.w * inv),
                         (short)f2bf(z1.x * inv), (short)f2bf(z1.y * inv),
                         (short)f2bf(z1.z * inv), (short)f2bf(z1.w * inv)};
            *(short8*)&outb[(size_t)(g >> 1) * T * 16 + (size_t)t * 16 + (g & 1) * 8] = ob;
        }
    }
}

// ---------------- layer-2 pre-projection GEMM: p = h @ [Wn|Ws] (128->128) ----
// A sliced [8][T][16]; output [16][T][8] (8-dim slices for agg64/combine).
__global__ __launch_bounds__(256) void proj2_kernel(
    const u16* __restrict__ A_i, const u16* __restrict__ wt_pi,
    u16* __restrict__ out_i, int ci,
    const u16* __restrict__ A_u, const u16* __restrict__ wt_pu,
    u16* __restrict__ out_u)
{
    constexpr int NF = 2;
    constexpr int FSTR = 132;
    __shared__ float smF[64 * FSTR];               // 33792 B; low half doubles as A
    u16* smA = (u16*)smF;                          // 64 x 136 u16

    const u16 *A, *Wt; u16* outb; int T, t0;
    if ((int)blockIdx.x < ci) {
        A = A_i; Wt = wt_pi; outb = out_i; T = NI; t0 = blockIdx.x * 64;
    } else {
        A = A_u; Wt = wt_pu; outb = out_u; T = NU; t0 = (blockIdx.x - ci) * 64;
    }

    const int tid  = threadIdx.x;
    const int wave = tid >> 6;
    const int lane = tid & 63;
    const int lr   = lane & 15;
    const int lg   = lane >> 4;

    // stage A from sliced [8][T][16]
    #pragma unroll
    for (int i = 0; i < 4; ++i) {
        int lin = i * 256 + tid;
        int row = lin >> 4;
        int q   = lin & 15;
        int t   = t0 + row; if (t >= T) t = T - 1;
        *(short8*)&smA[row * 136 + (q << 3)] =
            *(const short8*)&A[(size_t)(q >> 1) * T * 16 + (size_t)t * 16 + (q & 1) * 8];
    }
    __syncthreads();

    const u16* wp[NF];
    #pragma unroll
    for (int ni = 0; ni < NF; ++ni) {
        int col = wave * 32 + ni * 16 + lr;
        wp[ni] = Wt + (size_t)col * 128;
    }

    f32x4 acc[4][NF];
    #pragma unroll
    for (int mi = 0; mi < 4; ++mi)
        #pragma unroll
        for (int ni = 0; ni < NF; ++ni)
            acc[mi][ni] = (f32x4){0.f, 0.f, 0.f, 0.f};

    #pragma unroll
    for (int ks = 0; ks < 4; ++ks) {
        const int kb = ks * 32 + (lg << 3);
        short8 b[NF];
        #pragma unroll
        for (int ni = 0; ni < NF; ++ni) b[ni] = *(const short8*)&wp[ni][kb];
        #pragma unroll
        for (int mi = 0; mi < 4; ++mi) {
            short8 a = *(const short8*)&smA[(mi * 16 + lr) * 136 + kb];
            #pragma unroll
            for (int ni = 0; ni < NF; ++ni)
                acc[mi][ni] = __builtin_amdgcn_mfma_f32_16x16x32_bf16(a, b[ni], acc[mi][ni], 0, 0, 0);
        }
    }
    __syncthreads();

    #pragma unroll
    for (int mi = 0; mi < 4; ++mi)
        #pragma unroll
        for (int j = 0; j < 4; ++j) {
            int rowg = mi * 16 + lg * 4 + j;
            #pragma unroll
            for (int ni = 0; ni < NF; ++ni)
                smF[rowg * FSTR + wave * 32 + ni * 16 + lr] = acc[mi][ni][j];
        }
    __syncthreads();

    // store to [16][T][8]: chunk g == slice g
    #pragma unroll
    for (int i = 0; i < 4; ++i) {
        int lin = i * 256 + tid;
        int row = lin >> 4, g = lin & 15;
        int t = t0 + row;
        if (t < T) {
            float4 z0 = *(float4*)&smF[row * FSTR + g * 8];
            float4 z1 = *(float4*)&smF[row * FSTR + g * 8 + 4];
            short8 ob = {(short)f2bf(z0.x), (short)f2bf(z0.y),
                         (short)f2bf(z0.z), (short)f2bf(z0.w),
                         (short)f2bf(z1.x), (short)f2bf(z1.y),
                         (short)f2bf(z1.z), (short)f2bf(z1.w)};
            *(short8*)&outb[(size_t)g * T * 8 + (size_t)t * 8] = ob;
        }
    }
}

// ---------------- layer-2 combine: z = agg64 + self + biases; relu; L2-norm ----
// agg64 sliced [8][T][8]; proj [16][T][8] (self = slices 8..15).
__global__ __launch_bounds__(256) void combine2_kernel(
    const u16* __restrict__ agg_i, const u16* __restrict__ proj_i,
    const float* __restrict__ bn2, const float* __restrict__ bs2,
    float* __restrict__ outf_i, u16* __restrict__ outb_i, int cbi,
    const u16* __restrict__ agg_u, const u16* __restrict__ proj_u,
    float* __restrict__ outf_u, u16* __restrict__ outb_u)
{
    const u16 *agg, *proj; const float *bn, *bs; float* outf; u16* outb; int T, r0;
    if ((int)blockIdx.x < cbi) {
        agg = agg_i; proj = proj_i; bn = bn2;      bs = bs2;
        outf = outf_i; outb = outb_i; T = NI; r0 = blockIdx.x * 32;
    } else {
        agg = agg_u; proj = proj_u; bn = bn2 + 64; bs = bs2 + 64;
        outf = outf_u; outb = outb_u; T = NU; r0 = (blockIdx.x - cbi) * 32;
    }
    int g = threadIdx.x >> 3, l = threadIdx.x & 7;
    int r = r0 + g;
    if (r >= T) return;
    short8 va = *(const short8*)&agg[(size_t)l * T * 8 + (size_t)r * 8];
    short8 vs = *(const short8*)&proj[(size_t)(8 + l) * T * 8 + (size_t)r * 8];
    float z[8];
    float s = 0.f;
    #pragma unroll
    for (int q = 0; q < 8; ++q) {
        float v = bf2f((u16)va[q]) + bf2f((u16)vs[q]) + bn[l * 8 + q] + bs[l * 8 + q];
        v = fmaxf(v, 0.f);
        z[q] = v;
        s = fmaf(v, v, s);
    }
    s += __shfl_xor(s, 1);
    s += __shfl_xor(s, 2);
    s += __shfl_xor(s, 4);
    float inv = 1.f / fmaxf(sqrtf(s), 1e-12f);
    short8 ob;
    float4 o0, o1;
    o0.x = z[0] * inv; o0.y = z[1] * inv; o0.z = z[2] * inv; o0.w = z[3] * inv;
    o1.x = z[4] * inv; o1.y = z[5] * inv; o1.z = z[6] * inv; o1.w = z[7] * inv;
    #pragma unroll
    for (int q = 0; q < 8; ++q) ob[q] = (short)f2bf(z[q] * inv);
    *(short8*)&outb[(size_t)r * 64 + (l << 3)] = ob;
    *(float4*)&outf[(size_t)r * 64 + (l << 3)]     = o0;
    *(float4*)&outf[(size_t)r * 64 + (l << 3) + 4] = o1;
}

// ---------------- cosine scores, pos + neg in ONE launch (linear tables) ----
__global__ __launch_bounds__(256) void score2_kernel(
    const u16* __restrict__ hu, const u16* __restrict__ hi,
    const int* __restrict__ pu0, const int* __restrict__ pi0, float* __restrict__ out0,
    const int* __restrict__ pu1, const int* __restrict__ pi1, float* __restrict__ out1,
    int P) {
    const int *pu, *pi; float* out;
    if (blockIdx.y == 0) { pu = pu0; pi = pi0; out = out0; }
    else                 { pu = pu1; pi = pi1; out = out1; }
    int g = threadIdx.x >> 3, l = threadIdx.x & 7;
    int p = blockIdx.x * 32 + g;
    if (p >= P) return;
    int u = __builtin_nontemporal_load(&pu[p]);
    int it = __builtin_nontemporal_load(&pi[p]);
    short8 a = *(const short8*)&hu[(size_t)u * 64 + (l << 3)];
    short8 b = *(const short8*)&hi[(size_t)it * 64 + (l << 3)];
    float d = 0.f, na = 0.f, nb = 0.f;
    #pragma unroll
    for (int q = 0; q < 8; ++q) {
        float x = bf2f((u16)a[q]), y = bf2f((u16)b[q]);
        d  = fmaf(x, y, d);
        na = fmaf(x, x, na);
        nb = fmaf(y, y, nb);
    }
    #pragma unroll
    for (int m = 1; m < 8; m <<= 1) {
        d  += __shfl_xor(d, m);
        na += __shfl_xor(na, m);
        nb += __shfl_xor(nb, m);
    }
    if (l == 0) out[p] = d / (fmaxf(sqrtf(na), 1e-12f) * fmaxf(sqrtf(nb), 1e-12f));
}

// ---------------- host ----------------

extern "C" void kernel_launch(void* const* d_in, const int* in_sizes, int n_in,
                              void* d_out, int out_size, void* d_ws, size_t ws_size,
                              hipStream_t stream) {
    const float* h_user = (const float*)d_in[0];
    const float* h_item = (const float*)d_in[1];
    const float* Wn01   = (const float*)d_in[2];
    const float* bn01   = (const float*)d_in[3];
    const float* Ws01   = (const float*)d_in[4];
    const float* bs01   = (const float*)d_in[5];
    const float* Wn2    = (const float*)d_in[6];
    const float* bn2    = (const float*)d_in[7];
    const float* Ws2    = (const float*)d_in[8];
    const float* bs2    = (const float*)d_in[9];
    const int* u2i_src  = (const int*)d_in[10];
    const int* u2i_dst  = (const int*)d_in[11];
    const int* i2u_src  = (const int*)d_in[12];
    const int* i2u_dst  = (const int*)d_in[13];
    const int* pos_u    = (const int*)d_in[14];
    const int* pos_i    = (const int*)d_in[15];
    const int* neg_u    = (const int*)d_in[16];
    const int* neg_i    = (const int*)d_in[17];

    float* out = (float*)d_out;
    float* out_hu = out;                       // [NU,64]
    float* out_hi = out + (size_t)NU * 64;     // [NI,64]
    float* out_pos = out + (size_t)NU * 64 + (size_t)NI * 64;
    float* out_neg = out_pos + NP;

    // workspace layout
    char* ws = (char*)d_ws;
    size_t off = 0;
    auto alloc = [&](size_t bytes) -> void* {
        void* p = ws + off;
        off = (off + bytes + 255) & ~(size_t)255;
        return p;
    };
    u16* hu0b = (u16*)alloc((size_t)NU * 128 * 2);   // sliced bf16 input copies
    u16* hi0b = (u16*)alloc((size_t)NI * 128 * 2);
    u16* hu_b = (u16*)alloc((size_t)NU * 128 * 2);   // layer-0 out; layer-2 proj_u reuse
    u16* hi_b = (u16*)alloc((size_t)NI * 128 * 2);
    u16* hu_a = (u16*)alloc((size_t)NU * 128 * 2);   // layer-1 out
    u16* hi_a = (u16*)alloc((size_t)NI * 128 * 2);
    u16* agg_i = (u16*)alloc((size_t)NI * 128 * 2);  // agg outputs (sliced)
    u16* agg_u = (u16*)alloc((size_t)NU * 128 * 2);
    u16* hu2b = (u16*)alloc((size_t)NU * 64 * 2);    // final embeddings (linear)
    u16* hi2b = (u16*)alloc((size_t)NI * 64 * 2);
    u16* wt_all = (u16*)alloc((size_t)(4 * 128 * 256 + 2 * 128 * 128) * 2);
    u16* wt_l0_i = wt_all;                 // each 128x256
    u16* wt_l0_u = wt_all + 32768;
    u16* wt_l1_i = wt_all + 65536;
    u16* wt_l1_u = wt_all + 98304;
    u16* wt_pu   = wt_all + 131072;        // 128x128 [Wn2_i | Ws2_u]
    u16* wt_pi   = wt_all + 147456;        // 128x128 [Wn2_u | Ws2_i]
    int* csr_u2i = (int*)alloc((size_t)NE * 4);
    int* csr_i2u = (int*)alloc((size_t)NE * 4);
    int* rs_i   = (int*)alloc((size_t)(NI + 1) * 4);
    int* rs_u   = (int*)alloc((size_t)(NU + 1) * 4);
    int* deg    = (int*)alloc((size_t)(NI + NU) * 4);   // deg_i | deg_u
    int* bsum_i = (int*)alloc(1024 * 4);
    int* bsum_u = (int*)alloc(1024 * 4);
    int* deg_i = deg, *deg_u = deg + NI;
    // rank arrays alias the (not-yet-live) agg buffers
    int* rank_i = (int*)agg_i;
    int* rank_u = (int*)agg_u;
    // layer-2 reuse: proj [16][N][8] over dead layer-0 outs; agg64 over agg bufs
    u16* proj_u = hu_b;
    u16* proj_i = hi_b;
    u16* agg64_i = agg_i;
    u16* agg64_u = agg_u;
    (void)ws_size; (void)in_sizes; (void)n_in; (void)out_size;

    const int eblocks = (NE + 255) / 256;

    // ---- sliced bf16 input copies + all transposed bf16 weights ----
    cvt_kernel<<<(NU * 16 + 255) / 256, 256, 0, stream>>>(h_user, hu0b, NU);
    cvt_kernel<<<(NI * 16 + 255) / 256, 256, 0, stream>>>(h_item, hi0b, NI);
    wtrans_all_kernel<<<768, 128, 0, stream>>>(Wn01, Ws01, Wn2, Ws2, wt_all);

    // ---- CSR build (both directions, rank-based single-pass fill) ----
    hipMemsetAsync(deg, 0, (size_t)(NI + NU) * 4, stream);
    hist2_kernel<<<dim3(eblocks, 2), 256, 0, stream>>>(u2i_dst, deg_i, rank_i,
                                                       i2u_dst, deg_u, rank_u, NE);
    const int nb_i = (NI + 1023) / 1024, nb_u = (NU + 1023) / 1024;
    const int nb_max = (nb_i > nb_u) ? nb_i : nb_u;
    scan2_local_kernel<<<dim3(nb_max, 2), 1024, 0, stream>>>(
        deg_i, rs_i, bsum_i, NI, deg_u, rs_u, bsum_u, NU);
    scan2_bsum_kernel<<<dim3(1, 2), 1024, 0, stream>>>(bsum_i, nb_i, bsum_u, nb_u);
    scan2_finalize_kernel<<<dim3(nb_max, 2), 1024, 0, stream>>>(
        rs_i, bsum_i, NI, rs_u, bsum_u, NU, NE);
    fill2_kernel<<<dim3(eblocks, 2), 256, 0, stream>>>(
        u2i_src, u2i_dst, rank_i, rs_i, csr_u2i,
        i2u_src, i2u_dst, rank_u, rs_u, csr_i2u, NE);

    const int MI2 = (NI + 127) / 128, MU2 = (NU + 127) / 128;    // agg2 groups
    const int agg2_grid = 8 * (MI2 + MU2);
    const int MI64 = (NI + 255) / 256, MU64 = (NU + 255) / 256;  // agg64 groups
    const int agg64_grid = 8 * (MI64 + MU64);
    const int ci = (NI + 63) / 64, cu = (NU + 63) / 64;          // conv/proj
    const int cbi = (NI + 31) / 32, cbu = (NU + 31) / 32;        // combine

    // ---- layer 0 ----
    agg2_kernel<<<agg2_grid, 256, 0, stream>>>(hu0b, hi0b, rs_i, csr_u2i, agg_i,
                                               rs_u, csr_i2u, agg_u);
    conv2_kernel<<<ci + cu, 256, 0, stream>>>(
        agg_i, hi0b, wt_l0_i, bn01 + 0, bs01 + 0, hi_b, ci,
        agg_u, hu0b, wt_l0_u, bn01 + 128, bs01 + 128, hu_b);
    // ---- layer 1 ----
    agg2_kernel<<<agg2_grid, 256, 0, stream>>>(hu_b, hi_b, rs_i, csr_u2i, agg_i,
                                               rs_u, csr_i2u, agg_u);
    conv2_kernel<<<ci + cu, 256, 0, stream>>>(
        agg_i, hi_b, wt_l1_i, bn01 + 256, bs01 + 256, hi_a, ci,
        agg_u, hu_b, wt_l1_u, bn01 + 384, bs01 + 384, hu_a);
    // ---- layer 2: pre-project (mean(h)@W = mean(h@W)), 64-dim agg, combine ----
    proj2_kernel<<<ci + cu, 256, 0, stream>>>(hi_a, wt_pi, proj_i, ci,
                                              hu_a, wt_pu, proj_u);
    agg64_kernel<<<agg64_grid, 256, 0, stream>>>(proj_u, proj_i, rs_i, csr_u2i,
                                                 agg64_i,
                                                 rs_u, csr_i2u, agg64_u);
    combine2_kernel<<<cbi + cbu, 256, 0, stream>>>(
        agg64_i, proj_i, bn2, bs2, out_hi, hi2b, cbi,
        agg64_u, proj_u, out_hu, hu2b);

    // ---- cosine scores (pos + neg in one launch) ----
    score2_kernel<<<dim3((NP + 31) / 32, 2), 256, 0, stream>>>(
        hu2b, hi2b, pos_u, pos_i, out_pos, neg_u, neg_i, out_neg, NP);
}

// Round 16
// 531.061 us; speedup vs baseline: 1.5134x; 1.5134x over previous
//
#include <hip/hip_runtime.h>
#include <hip/hip_bf16.h>

// Problem constants (from reference)
#define NU 100000
#define NI 50000
#define NE 1000000
#define NP 500000
// D_IN = D_HID = 128, D_OUT = 64

typedef unsigned short u16;
typedef unsigned int u32;
typedef __attribute__((ext_vector_type(8))) short short8;   // 8 bf16 (4 VGPRs)
typedef __attribute__((ext_vector_type(4))) float f32x4;

static __device__ __forceinline__ u16 f2bf(float f) {
    union { float f; u32 u; } x; x.f = f;
    u32 r = x.u + 0x7fff + ((x.u >> 16) & 1);   // round-to-nearest-even
    return (u16)(r >> 16);
}
static __device__ __forceinline__ float bf2f(u16 h) {
    union { u32 u; float f; } x; x.u = ((u32)h) << 16;
    return x.f;
}

// NOTE (r15 lesson): all feature tables are LINEAR [N][128]/[N][64] bf16.
// Dim-sliced layouts (32B rows) regressed 2.3x: random gathers must keep
// row granularity >= cache line. agg2 at r14 layout is ~at the LLC
// random-gather floor (FETCH ~ 8-XCD-replicated table).

// ---------------- f32 -> bf16 table conversion ----------------
__global__ __launch_bounds__(256) void cvt_kernel(const float* __restrict__ in,
                                                  u16* __restrict__ out, int n8) {
    int i = blockIdx.x * blockDim.x + threadIdx.x;
    if (i >= n8) return;
    float4 a = ((const float4*)in)[2 * i];
    float4 b = ((const float4*)in)[2 * i + 1];
    ushort4 lo = {f2bf(a.x), f2bf(a.y), f2bf(a.z), f2bf(a.w)};
    ushort4 hi = {f2bf(b.x), f2bf(b.y), f2bf(b.z), f2bf(b.w)};
    ((ushort4*)out)[2 * i]     = lo;
    ((ushort4*)out)[2 * i + 1] = hi;
}

// ---------------- weight transposes in one launch ----------------
// wt layout (u16): 4 x (128x256) layers 0/1 [n][k], then wt_pu (128x128) and
// wt_pi (128x128) for the layer-2 pre-projection:
//   wt_pu: cols 0..63 = Wn2_i (items' neighbor proj), 64..127 = Ws2_u (users' self)
//   wt_pi: cols 0..63 = Wn2_u (users' neighbor proj), 64..127 = Ws2_i (items' self)
__global__ void wtrans_all_kernel(const float* __restrict__ Wn01,
                                  const float* __restrict__ Ws01,
                                  const float* __restrict__ Wn2,
                                  const float* __restrict__ Ws2,
                                  u16* __restrict__ wt) {
    int x = blockIdx.x;            // 0..767
    int k = threadIdx.x;           // 0..127
    if (x < 512) {
        int m = x >> 7, n = x & 127;
        const float* Wn = Wn01 + m * 16384;
        const float* Ws = Ws01 + m * 16384;
        size_t o = (size_t)m * 128 * 256;
        wt[o + (size_t)n * 256 + k]       = f2bf(Wn[(size_t)k * 128 + n]);
        wt[o + (size_t)n * 256 + 128 + k] = f2bf(Ws[(size_t)k * 128 + n]);
    } else {
        int m = (x - 512) >> 7;    // 0 = pu, 1 = pi
        int n = (x - 512) & 127;
        size_t o = 131072 + (size_t)m * 16384;
        float v;
        if (m == 0) v = (n < 64) ? Wn2[(size_t)k * 64 + n]
                                 : Ws2[8192 + (size_t)k * 64 + (n - 64)];
        else        v = (n < 64) ? Wn2[8192 + (size_t)k * 64 + n]
                                 : Ws2[(size_t)k * 64 + (n - 64)];
        wt[o + (size_t)n * 128 + k] = f2bf(v);
    }
}

// ---------------- CSR build ----------------

__global__ void hist2_kernel(const int* __restrict__ d0, int* __restrict__ deg0,
                             int* __restrict__ rank0,
                             const int* __restrict__ d1, int* __restrict__ deg1,
                             int* __restrict__ rank1, int E) {
    int e = blockIdx.x * blockDim.x + threadIdx.x;
    if (e >= E) return;
    if (blockIdx.y == 0) {
        int d = __builtin_nontemporal_load(&d0[e]);
        int r = atomicAdd(&deg0[d], 1);
        __builtin_nontemporal_store(r, &rank0[e]);
    } else {
        int d = __builtin_nontemporal_load(&d1[e]);
        int r = atomicAdd(&deg1[d], 1);
        __builtin_nontemporal_store(r, &rank1[e]);
    }
}

__global__ void scan2_local_kernel(const int* __restrict__ in0, int* __restrict__ out0,
                                   int* __restrict__ bsum0, int n0,
                                   const int* __restrict__ in1, int* __restrict__ out1,
                                   int* __restrict__ bsum1, int n1) {
    const int* in; int *out, *bsum; int n;
    if (blockIdx.y == 0) { in = in0; out = out0; bsum = bsum0; n = n0; }
    else                 { in = in1; out = out1; bsum = bsum1; n = n1; }
    __shared__ int s[1024];
    int i = blockIdx.x * 1024 + threadIdx.x;
    int v = (i < n) ? in[i] : 0;
    s[threadIdx.x] = v;
    __syncthreads();
    for (int off = 1; off < 1024; off <<= 1) {
        int t = (threadIdx.x >= off) ? s[threadIdx.x - off] : 0;
        __syncthreads();
        s[threadIdx.x] += t;
        __syncthreads();
    }
    if (i < n) out[i] = s[threadIdx.x] - v;   // exclusive within block
    if (threadIdx.x == 1023) bsum[blockIdx.x] = s[1023];
}

__global__ void scan2_bsum_kernel(int* b0, int nb0, int* b1, int nb1) {
    int* bsum; int nb;
    if (blockIdx.y == 0) { bsum = b0; nb = nb0; }
    else                 { bsum = b1; nb = nb1; }
    __shared__ int s[1024];
    int v = ((int)threadIdx.x < nb) ? bsum[threadIdx.x] : 0;
    s[threadIdx.x] = v;
    __syncthreads();
    for (int off = 1; off < 1024; off <<= 1) {
        int t = (threadIdx.x >= off) ? s[threadIdx.x - off] : 0;
        __syncthreads();
        s[threadIdx.x] += t;
        __syncthreads();
    }
    if ((int)threadIdx.x < nb) bsum[threadIdx.x] = s[threadIdx.x] - v;  // exclusive
}

__global__ void scan2_finalize_kernel(int* __restrict__ rs0, const int* __restrict__ b0,
                                      int n0, int* __restrict__ rs1,
                                      const int* __restrict__ b1, int n1, int E) {
    int* rs; const int* bsum; int n;
    if (blockIdx.y == 0) { rs = rs0; bsum = b0; n = n0; }
    else                 { rs = rs1; bsum = b1; n = n1; }
    int i = blockIdx.x * 1024 + threadIdx.x;
    if (i < n) rs[i] += bsum[blockIdx.x];
    if (i == 0) rs[n] = E;
}

// single-pass atomic-free fill: csr[rs[d] + rank[e]] = src[e].
__global__ void fill2_kernel(const int* __restrict__ s0, const int* __restrict__ d0,
                             const int* __restrict__ r0, const int* __restrict__ rs0,
                             int* __restrict__ csr0,
                             const int* __restrict__ s1, const int* __restrict__ d1,
                             const int* __restrict__ r1, const int* __restrict__ rs1,
                             int* __restrict__ csr1, int E) {
    const int *src, *dst, *rk, *rs; int* csr;
    if (blockIdx.y == 0) { src = s0; dst = d0; rk = r0; rs = rs0; csr = csr0; }
    else                 { src = s1; dst = d1; rk = r1; rs = rs1; csr = csr1; }
    int e = blockIdx.x * blockDim.x + threadIdx.x;
    if (e >= E) return;
    int d = __builtin_nontemporal_load(&dst[e]);
    int r = __builtin_nontemporal_load(&rk[e]);
    int s = __builtin_nontemporal_load(&src[e]);
    csr[rs[d] + r] = s;
}

// ---------------- mean aggregation, items + users in ONE launch ----------------
// r14 version (at LLC random-gather floor). 16 lanes own one node (8 dims/lane
// = full 128-dim row; no end shuffle, direct store); 4-deep edge unroll.
__global__ __launch_bounds__(256) void agg2_kernel(
    const u16* __restrict__ hu, const u16* __restrict__ hi,
    const int* __restrict__ rs_i, const int* __restrict__ csr_i,
    u16* __restrict__ out_i, int gi2,
    const int* __restrict__ rs_u, const int* __restrict__ csr_u,
    u16* __restrict__ out_u) {
    const u16* hsrc; const int *rs, *csr; u16* out; int T, t;
    int bx = blockIdx.x;
    int grp = threadIdx.x >> 4;        // 0..15 node groups per block
    int lr  = threadIdx.x & 15;        // dims lr*8 .. lr*8+7
    if (bx < gi2) { hsrc = hu; rs = rs_i; csr = csr_i; out = out_i; T = NI;
                    t = bx * 16 + grp; }
    else          { hsrc = hi; rs = rs_u; csr = csr_u; out = out_u; T = NU;
                    t = (bx - gi2) * 16 + grp; }
    if (t >= T) return;
    int e0 = rs[t], e1 = rs[t + 1];
    float acc[8] = {};
    int e = e0;
    for (; e + 3 < e1; e += 4) {       // 4 gathers in flight per group
        int s0 = __builtin_nontemporal_load(&csr[e]);
        int s1 = __builtin_nontemporal_load(&csr[e + 1]);
        int s2 = __builtin_nontemporal_load(&csr[e + 2]);
        int s3 = __builtin_nontemporal_load(&csr[e + 3]);
        short8 v0 = *(const short8*)&hsrc[(size_t)s0 * 128 + (lr << 3)];
        short8 v1 = *(const short8*)&hsrc[(size_t)s1 * 128 + (lr << 3)];
        short8 v2 = *(const short8*)&hsrc[(size_t)s2 * 128 + (lr << 3)];
        short8 v3 = *(const short8*)&hsrc[(size_t)s3 * 128 + (lr << 3)];
        #pragma unroll
        for (int q = 0; q < 8; ++q)
            acc[q] += (bf2f((u16)v0[q]) + bf2f((u16)v1[q])) +
                      (bf2f((u16)v2[q]) + bf2f((u16)v3[q]));
    }
    for (; e < e1; ++e) {
        int s0 = __builtin_nontemporal_load(&csr[e]);
        short8 v0 = *(const short8*)&hsrc[(size_t)s0 * 128 + (lr << 3)];
        #pragma unroll
        for (int q = 0; q < 8; ++q) acc[q] += bf2f((u16)v0[q]);
    }
    float inv = (e1 > e0) ? 1.f / (float)(e1 - e0) : 0.f;
    short8 o;
    #pragma unroll
    for (int q = 0; q < 8; ++q) o[q] = (short)f2bf(acc[q] * inv);
    __builtin_nontemporal_store(o, (short8*)&out[(size_t)t * 128 + (lr << 3)]);
}

// ---------------- layer-2: 64-dim aggregation over projected tables ----------------
// Gathers only cols 0..63 (first 128B) of the [*,128] projected rows.
__global__ __launch_bounds__(256) void agg64_kernel(
    const u16* __restrict__ pu, const u16* __restrict__ pi,
    const int* __restrict__ rs_i, const int* __restrict__ csr_i,
    u16* __restrict__ out_i, int gi64,
    const int* __restrict__ rs_u, const int* __restrict__ csr_u,
    u16* __restrict__ out_u) {
    const u16* hsrc; const int *rs, *csr; u16* out; int T, t;
    int bx = blockIdx.x;
    int grp = threadIdx.x >> 3;        // 0..31 node groups per block
    int lr  = threadIdx.x & 7;         // dims lr*8 .. lr*8+7
    if (bx < gi64) { hsrc = pu; rs = rs_i; csr = csr_i; out = out_i; T = NI;
                     t = bx * 32 + grp; }
    else           { hsrc = pi; rs = rs_u; csr = csr_u; out = out_u; T = NU;
                     t = (bx - gi64) * 32 + grp; }
    if (t >= T) return;
    int e0 = rs[t], e1 = rs[t + 1];
    float acc[8] = {};
    int e = e0;
    for (; e + 3 < e1; e += 4) {
        int s0 = __builtin_nontemporal_load(&csr[e]);
        int s1 = __builtin_nontemporal_load(&csr[e + 1]);
        int s2 = __builtin_nontemporal_load(&csr[e + 2]);
        int s3 = __builtin_nontemporal_load(&csr[e + 3]);
        short8 v0 = *(const short8*)&hsrc[(size_t)s0 * 128 + (lr << 3)];
        short8 v1 = *(const short8*)&hsrc[(size_t)s1 * 128 + (lr << 3)];
        short8 v2 = *(const short8*)&hsrc[(size_t)s2 * 128 + (lr << 3)];
        short8 v3 = *(const short8*)&hsrc[(size_t)s3 * 128 + (lr << 3)];
        #pragma unroll
        for (int q = 0; q < 8; ++q)
            acc[q] += (bf2f((u16)v0[q]) + bf2f((u16)v1[q])) +
                      (bf2f((u16)v2[q]) + bf2f((u16)v3[q]));
    }
    for (; e < e1; ++e) {
        int s0 = __builtin_nontemporal_load(&csr[e]);
        short8 v0 = *(const short8*)&hsrc[(size_t)s0 * 128 + (lr << 3)];
        #pragma unroll
        for (int q = 0; q < 8; ++q) acc[q] += bf2f((u16)v0[q]);
    }
    float inv = (e1 > e0) ? 1.f / (float)(e1 - e0) : 0.f;
    short8 o;
    #pragma unroll
    for (int q = 0; q < 8; ++q) o[q] = (short)f2bf(acc[q] * inv);
    __builtin_nontemporal_store(o, (short8*)&out[(size_t)t * 64 + (lr << 3)]);
}

// ---------------- conv via MFMA (layers 0/1), items + users in ONE launch ----
// z = [hn|hd] @ Wt^T + bn + bs; relu; row L2-norm. 4 waves, 32-row tile.
// TM=32 (was 64): LDS 17.5KB -> 8 blocks/CU = 100% wave occupancy (r8/r14
// showed these kernels latency-bound at 50% occupancy, MfmaUtil ~4%).
__global__ __launch_bounds__(256) void conv2_kernel(
    const u16* __restrict__ hn_i, const u16* __restrict__ hd_i,
    const u16* __restrict__ wt_i, const float* __restrict__ bn_i,
    const float* __restrict__ bs_i, u16* __restrict__ outb_i, int ci,
    const u16* __restrict__ hn_u, const u16* __restrict__ hd_u,
    const u16* __restrict__ wt_u, const float* __restrict__ bn_u,
    const float* __restrict__ bs_u, u16* __restrict__ outb_u)
{
    constexpr int NF   = 2;
    constexpr int FSTR = 132;
    __shared__ u16 smA[32 * 264];                  // 16896 B, reused as f32 out
    __shared__ float psum[4][32];
    __shared__ float sinv[32];
    float* smF = (float*)smA;

    const u16 *hn, *hd, *Wt; const float *bn, *bs; u16* outb; int T, t0;
    if ((int)blockIdx.x < ci) {
        hn = hn_i; hd = hd_i; Wt = wt_i; bn = bn_i; bs = bs_i;
        outb = outb_i; T = NI; t0 = blockIdx.x * 32;
    } else {
        hn = hn_u; hd = hd_u; Wt = wt_u; bn = bn_u; bs = bs_u;
        outb = outb_u; T = NU; t0 = (blockIdx.x - ci) * 32;
    }

    const int tid  = threadIdx.x;
    const int wave = tid >> 6;
    const int lane = tid & 63;
    const int lr   = lane & 15;
    const int lg   = lane >> 4;

    // stage A = [hn | hd]: 32 rows x 32 chunks of 16B
    #pragma unroll
    for (int i = 0; i < 4; ++i) {
        int lin = i * 256 + tid;
        int row = lin >> 5;
        int q   = lin & 31;
        int t   = t0 + row; if (t >= T) t = T - 1;
        const u16* srcp = (q < 16) ? &hn[(size_t)t * 128 + (q << 3)]
                                   : &hd[(size_t)t * 128 + ((q - 16) << 3)];
        *(short8*)&smA[row * 264 + (q << 3)] = *(const short8*)srcp;
    }
    __syncthreads();

    const u16* wp[NF];
    float bias[NF];
    #pragma unroll
    for (int ni = 0; ni < NF; ++ni) {
        int col = wave * 32 + ni * 16 + lr;
        wp[ni] = Wt + (size_t)col * 256;
        bias[ni] = bn[col] + bs[col];
    }

    f32x4 acc[2][NF];
    #pragma unroll
    for (int mi = 0; mi < 2; ++mi)
        #pragma unroll
        for (int ni = 0; ni < NF; ++ni)
            acc[mi][ni] = (f32x4){0.f, 0.f, 0.f, 0.f};

    #pragma unroll
    for (int ks = 0; ks < 8; ++ks) {
        const int kb = ks * 32 + (lg << 3);
        short8 b[NF];
        #pragma unroll
        for (int ni = 0; ni < NF; ++ni) b[ni] = *(const short8*)&wp[ni][kb];
        #pragma unroll
        for (int mi = 0; mi < 2; ++mi) {
            short8 a = *(const short8*)&smA[(mi * 16 + lr) * 264 + kb];
            #pragma unroll
            for (int ni = 0; ni < NF; ++ni)
                acc[mi][ni] = __builtin_amdgcn_mfma_f32_16x16x32_bf16(a, b[ni], acc[mi][ni], 0, 0, 0);
        }
    }
    __syncthreads();

    float rsum[2][4];
    #pragma unroll
    for (int mi = 0; mi < 2; ++mi) {
        #pragma unroll
        for (int j = 0; j < 4; ++j) {
            int rowg = mi * 16 + lg * 4 + j;
            float s = 0.f;
            #pragma unroll
            for (int ni = 0; ni < NF; ++ni) {
                float z = fmaxf(acc[mi][ni][j] + bias[ni], 0.f);
                int colg = wave * 32 + ni * 16 + lr;
                smF[rowg * FSTR + colg] = z;
                s = fmaf(z, z, s);
            }
            rsum[mi][j] = s;
        }
    }
    #pragma unroll
    for (int m = 1; m < 16; m <<= 1)
        #pragma unroll
        for (int mi = 0; mi < 2; ++mi)
            #pragma unroll
            for (int j = 0; j < 4; ++j)
                rsum[mi][j] += __shfl_xor(rsum[mi][j], m);
    if (lr == 0) {
        #pragma unroll
        for (int mi = 0; mi < 2; ++mi)
            #pragma unroll
            for (int j = 0; j < 4; ++j)
                psum[wave][mi * 16 + lg * 4 + j] = rsum[mi][j];
    }
    __syncthreads();
    if (tid < 32) {
        float n2 = psum[0][tid] + psum[1][tid] + psum[2][tid] + psum[3][tid];
        sinv[tid] = 1.f / fmaxf(sqrtf(n2), 1e-12f);
    }
    __syncthreads();

    // coalesced readback + store: 32 rows x 16 chunks of 8 cols
    #pragma unroll
    for (int i = 0; i < 2; ++i) {
        int lin = i * 256 + tid;
        int row = lin >> 4, g = lin & 15;
        int t = t0 + row;
        if (t < T) {
            float inv = sinv[row];
            float4 z0 = *(float4*)&smF[row * FSTR + g * 8];
            float4 z1 = *(float4*)&smF[row * FSTR + g * 8 + 4];
            short8 ob = {(short)f2bf(z0.x * inv), (short)f2bf(z0.y * inv),
                         (short)f2bf(z0.z * inv), (short)f2bf(z0.w * inv),
                         (short)f2bf(z1.x * inv), (short)f2bf(z1.y * inv),
                         (short)f2bf(z1.z * inv), (short)f2bf(z1.w * inv)};
            *(short8*)&outb[(size_t)t * 128 + g * 8] = ob;
        }
    }
}

// ---------------- layer-2 pre-projection GEMM: p = h @ [Wn|Ws] (128->128) ----
// No bias/relu/norm. TM=32 tile (occupancy, same as conv2).
__global__ __launch_bounds__(256) void proj2_kernel(
    const u16* __restrict__ A_i, const u16* __restrict__ wt_pi,
    u16* __restrict__ out_i, int ci,
    const u16* __restrict__ A_u, const u16* __restrict__ wt_pu,
    u16* __restrict__ out_u)
{
    constexpr int NF = 2;
    constexpr int FSTR = 132;
    __shared__ float smF[32 * FSTR];               // 16896 B; low half doubles as A
    u16* smA = (u16*)smF;                          // 32 x 136 u16 = 8704 B

    const u16 *A, *Wt; u16* outb; int T, t0;
    if ((int)blockIdx.x < ci) {
        A = A_i; Wt = wt_pi; outb = out_i; T = NI; t0 = blockIdx.x * 32;
    } else {
        A = A_u; Wt = wt_pu; outb = out_u; T = NU; t0 = (blockIdx.x - ci) * 32;
    }

    const int tid  = threadIdx.x;
    const int wave = tid >> 6;
    const int lane = tid & 63;
    const int lr   = lane & 15;
    const int lg   = lane >> 4;

    // stage A: 32 rows x 16 chunks of 16B, stride 136
    #pragma unroll
    for (int i = 0; i < 2; ++i) {
        int lin = i * 256 + tid;
        int row = lin >> 4;
        int q   = lin & 15;
        int t   = t0 + row; if (t >= T) t = T - 1;
        *(short8*)&smA[row * 136 + (q << 3)] =
            *(const short8*)&A[(size_t)t * 128 + (q << 3)];
    }
    __syncthreads();

    const u16* wp[NF];
    #pragma unroll
    for (int ni = 0; ni < NF; ++ni) {
        int col = wave * 32 + ni * 16 + lr;
        wp[ni] = Wt + (size_t)col * 128;
    }

    f32x4 acc[2][NF];
    #pragma unroll
    for (int mi = 0; mi < 2; ++mi)
        #pragma unroll
        for (int ni = 0; ni < NF; ++ni)
            acc[mi][ni] = (f32x4){0.f, 0.f, 0.f, 0.f};

    #pragma unroll
    for (int ks = 0; ks < 4; ++ks) {
        const int kb = ks * 32 + (lg << 3);
        short8 b[NF];
        #pragma unroll
        for (int ni = 0; ni < NF; ++ni) b[ni] = *(const short8*)&wp[ni][kb];
        #pragma unroll
        for (int mi = 0; mi < 2; ++mi) {
            short8 a = *(const short8*)&smA[(mi * 16 + lr) * 136 + kb];
            #pragma unroll
            for (int ni = 0; ni < NF; ++ni)
                acc[mi][ni] = __builtin_amdgcn_mfma_f32_16x16x32_bf16(a, b[ni], acc[mi][ni], 0, 0, 0);
        }
    }
    __syncthreads();

    // acc -> LDS transpose buffer (no bias/relu/norm)
    #pragma unroll
    for (int mi = 0; mi < 2; ++mi)
        #pragma unroll
        for (int j = 0; j < 4; ++j) {
            int rowg = mi * 16 + lg * 4 + j;
            #pragma unroll
            for (int ni = 0; ni < NF; ++ni)
                smF[rowg * FSTR + wave * 32 + ni * 16 + lr] = acc[mi][ni][j];
        }
    __syncthreads();

    #pragma unroll
    for (int i = 0; i < 2; ++i) {
        int lin = i * 256 + tid;
        int row = lin >> 4, g = lin & 15;
        int t = t0 + row;
        if (t < T) {
            float4 z0 = *(float4*)&smF[row * FSTR + g * 8];
            float4 z1 = *(float4*)&smF[row * FSTR + g * 8 + 4];
            short8 ob = {(short)f2bf(z0.x), (short)f2bf(z0.y),
                         (short)f2bf(z0.z), (short)f2bf(z0.w),
                         (short)f2bf(z1.x), (short)f2bf(z1.y),
                         (short)f2bf(z1.z), (short)f2bf(z1.w)};
            *(short8*)&outb[(size_t)t * 128 + g * 8] = ob;
        }
    }
}

// ---------------- layer-2 combine: z = agg64 + self + biases; relu; L2-norm ----
// 32 rows x 8 lanes per block; lane owns 8 dims. Writes f32 d_out + bf16 copy.
__global__ __launch_bounds__(256) void combine2_kernel(
    const u16* __restrict__ agg_i, const u16* __restrict__ proj_i,
    const float* __restrict__ bn2, const float* __restrict__ bs2,
    float* __restrict__ outf_i, u16* __restrict__ outb_i, int cbi,
    const u16* __restrict__ agg_u, const u16* __restrict__ proj_u,
    float* __restrict__ outf_u, u16* __restrict__ outb_u)
{
    const u16 *agg, *proj; const float *bn, *bs; float* outf; u16* outb; int T, r0;
    if ((int)blockIdx.x < cbi) {
        agg = agg_i; proj = proj_i; bn = bn2;      bs = bs2;
        outf = outf_i; outb = outb_i; T = NI; r0 = blockIdx.x * 32;
    } else {
        agg = agg_u; proj = proj_u; bn = bn2 + 64; bs = bs2 + 64;
        outf = outf_u; outb = outb_u; T = NU; r0 = (blockIdx.x - cbi) * 32;
    }
    int g = threadIdx.x >> 3, l = threadIdx.x & 7;
    int r = r0 + g;
    if (r >= T) return;
    short8 va = *(const short8*)&agg[(size_t)r * 64 + (l << 3)];
    short8 vs = *(const short8*)&proj[(size_t)r * 128 + 64 + (l << 3)];
    float z[8];
    float s = 0.f;
    #pragma unroll
    for (int q = 0; q < 8; ++q) {
        float v = bf2f((u16)va[q]) + bf2f((u16)vs[q]) + bn[l * 8 + q] + bs[l * 8 + q];
        v = fmaxf(v, 0.f);
        z[q] = v;
        s = fmaf(v, v, s);
    }
    s += __shfl_xor(s, 1);
    s += __shfl_xor(s, 2);
    s += __shfl_xor(s, 4);
    float inv = 1.f / fmaxf(sqrtf(s), 1e-12f);
    short8 ob;
    float4 o0, o1;
    o0.x = z[0] * inv; o0.y = z[1] * inv; o0.z = z[2] * inv; o0.w = z[3] * inv;
    o1.x = z[4] * inv; o1.y = z[5] * inv; o1.z = z[6] * inv; o1.w = z[7] * inv;
    #pragma unroll
    for (int q = 0; q < 8; ++q) ob[q] = (short)f2bf(z[q] * inv);
    *(short8*)&outb[(size_t)r * 64 + (l << 3)] = ob;
    *(float4*)&outf[(size_t)r * 64 + (l << 3)]     = o0;
    *(float4*)&outf[(size_t)r * 64 + (l << 3) + 4] = o1;
}

// ---------------- cosine scores, pos + neg in ONE launch ----------------
__global__ __launch_bounds__(256) void score2_kernel(
    const u16* __restrict__ hu, const u16* __restrict__ hi,
    const int* __restrict__ pu0, const int* __restrict__ pi0, float* __restrict__ out0,
    const int* __restrict__ pu1, const int* __restrict__ pi1, float* __restrict__ out1,
    int P) {
    const int *pu, *pi; float* out;
    if (blockIdx.y == 0) { pu = pu0; pi = pi0; out = out0; }
    else                 { pu = pu1; pi = pi1; out = out1; }
    int g = threadIdx.x >> 3, l = threadIdx.x & 7;
    int p = blockIdx.x * 32 + g;
    if (p >= P) return;
    int u = __builtin_nontemporal_load(&pu[p]);
    int it = __builtin_nontemporal_load(&pi[p]);
    short8 a = *(const short8*)&hu[(size_t)u * 64 + (l << 3)];
    short8 b = *(const short8*)&hi[(size_t)it * 64 + (l << 3)];
    float d = 0.f, na = 0.f, nb = 0.f;
    #pragma unroll
    for (int q = 0; q < 8; ++q) {
        float x = bf2f((u16)a[q]), y = bf2f((u16)b[q]);
        d  = fmaf(x, y, d);
        na = fmaf(x, x, na);
        nb = fmaf(y, y, nb);
    }
    #pragma unroll
    for (int m = 1; m < 8; m <<= 1) {
        d  += __shfl_xor(d, m);
        na += __shfl_xor(na, m);
        nb += __shfl_xor(nb, m);
    }
    if (l == 0) out[p] = d / (fmaxf(sqrtf(na), 1e-12f) * fmaxf(sqrtf(nb), 1e-12f));
}

// ---------------- host ----------------

extern "C" void kernel_launch(void* const* d_in, const int* in_sizes, int n_in,
                              void* d_out, int out_size, void* d_ws, size_t ws_size,
                              hipStream_t stream) {
    const float* h_user = (const float*)d_in[0];
    const float* h_item = (const float*)d_in[1];
    const float* Wn01   = (const float*)d_in[2];
    const float* bn01   = (const float*)d_in[3];
    const float* Ws01   = (const float*)d_in[4];
    const float* bs01   = (const float*)d_in[5];
    const float* Wn2    = (const float*)d_in[6];
    const float* bn2    = (const float*)d_in[7];
    const float* Ws2    = (const float*)d_in[8];
    const float* bs2    = (const float*)d_in[9];
    const int* u2i_src  = (const int*)d_in[10];
    const int* u2i_dst  = (const int*)d_in[11];
    const int* i2u_src  = (const int*)d_in[12];
    const int* i2u_dst  = (const int*)d_in[13];
    const int* pos_u    = (const int*)d_in[14];
    const int* pos_i    = (const int*)d_in[15];
    const int* neg_u    = (const int*)d_in[16];
    const int* neg_i    = (const int*)d_in[17];

    float* out = (float*)d_out;
    float* out_hu = out;                       // [NU,64]
    float* out_hi = out + (size_t)NU * 64;     // [NI,64]
    float* out_pos = out + (size_t)NU * 64 + (size_t)NI * 64;
    float* out_neg = out_pos + NP;

    // workspace layout
    char* ws = (char*)d_ws;
    size_t off = 0;
    auto alloc = [&](size_t bytes) -> void* {
        void* p = ws + off;
        off = (off + bytes + 255) & ~(size_t)255;
        return p;
    };
    u16* hu0b = (u16*)alloc((size_t)NU * 128 * 2);   // bf16 copies of inputs
    u16* hi0b = (u16*)alloc((size_t)NI * 128 * 2);
    u16* hu_b = (u16*)alloc((size_t)NU * 128 * 2);   // layer-0 out; layer-2 proj_u reuse
    u16* hi_b = (u16*)alloc((size_t)NI * 128 * 2);   // layer-0 out; layer-2 proj_i reuse
    u16* hu_a = (u16*)alloc((size_t)NU * 128 * 2);   // layer-1 out
    u16* hi_a = (u16*)alloc((size_t)NI * 128 * 2);
    u16* agg_i = (u16*)alloc((size_t)NI * 128 * 2);  // agg outputs (bf16)
    u16* agg_u = (u16*)alloc((size_t)NU * 128 * 2);
    u16* hu2b = (u16*)alloc((size_t)NU * 64 * 2);    // final embeddings (bf16, scores)
    u16* hi2b = (u16*)alloc((size_t)NI * 64 * 2);
    u16* wt_all = (u16*)alloc((size_t)(4 * 128 * 256 + 2 * 128 * 128) * 2);
    u16* wt_l0_i = wt_all;                 // each 128x256
    u16* wt_l0_u = wt_all + 32768;
    u16* wt_l1_i = wt_all + 65536;
    u16* wt_l1_u = wt_all + 98304;
    u16* wt_pu   = wt_all + 131072;        // 128x128 [Wn2_i | Ws2_u]
    u16* wt_pi   = wt_all + 147456;        // 128x128 [Wn2_u | Ws2_i]
    int* csr_u2i = (int*)alloc((size_t)NE * 4);
    int* csr_i2u = (int*)alloc((size_t)NE * 4);
    int* rs_i   = (int*)alloc((size_t)(NI + 1) * 4);
    int* rs_u   = (int*)alloc((size_t)(NU + 1) * 4);
    int* deg    = (int*)alloc((size_t)(NI + NU) * 4);   // deg_i | deg_u
    int* bsum_i = (int*)alloc(1024 * 4);
    int* bsum_u = (int*)alloc(1024 * 4);
    int* deg_i = deg, *deg_u = deg + NI;
    // rank arrays alias the (not-yet-live) agg buffers (hist2/fill2 complete
    // before the first agg2 writes them; single stream = sequential).
    int* rank_i = (int*)agg_i;
    int* rank_u = (int*)agg_u;
    // layer-2: proj buffers reuse the dead layer-0 outputs; agg64 reuses agg bufs
    u16* proj_u = hu_b;
    u16* proj_i = hi_b;
    u16* agg64_i = agg_i;
    u16* agg64_u = agg_u;
    (void)ws_size; (void)in_sizes; (void)n_in; (void)out_size;

    const int eblocks = (NE + 255) / 256;

    // ---- bf16 copies of input features + all transposed bf16 weights ----
    cvt_kernel<<<(NU * 128 / 8 + 255) / 256, 256, 0, stream>>>(h_user, hu0b, NU * 128 / 8);
    cvt_kernel<<<(NI * 128 / 8 + 255) / 256, 256, 0, stream>>>(h_item, hi0b, NI * 128 / 8);
    wtrans_all_kernel<<<768, 128, 0, stream>>>(Wn01, Ws01, Wn2, Ws2, wt_all);

    // ---- CSR build (both directions, rank-based single-pass fill) ----
    hipMemsetAsync(deg, 0, (size_t)(NI + NU) * 4, stream);
    hist2_kernel<<<dim3(eblocks, 2), 256, 0, stream>>>(u2i_dst, deg_i, rank_i,
                                                       i2u_dst, deg_u, rank_u, NE);
    const int nb_i = (NI + 1023) / 1024, nb_u = (NU + 1023) / 1024;
    const int nb_max = (nb_i > nb_u) ? nb_i : nb_u;
    scan2_local_kernel<<<dim3(nb_max, 2), 1024, 0, stream>>>(
        deg_i, rs_i, bsum_i, NI, deg_u, rs_u, bsum_u, NU);
    scan2_bsum_kernel<<<dim3(1, 2), 1024, 0, stream>>>(bsum_i, nb_i, bsum_u, nb_u);
    scan2_finalize_kernel<<<dim3(nb_max, 2), 1024, 0, stream>>>(
        rs_i, bsum_i, NI, rs_u, bsum_u, NU, NE);
    fill2_kernel<<<dim3(eblocks, 2), 256, 0, stream>>>(
        u2i_src, u2i_dst, rank_i, rs_i, csr_u2i,
        i2u_src, i2u_dst, rank_u, rs_u, csr_i2u, NE);

    const int gi2 = (NI + 15) / 16, gu2 = (NU + 15) / 16;    // agg2 sub-grids
    const int gi64 = (NI + 31) / 32, gu64 = (NU + 31) / 32;  // agg64 sub-grids
    const int ci = (NI + 31) / 32, cu = (NU + 31) / 32;      // conv/proj sub-grids (TM=32)
    const int cbi = (NI + 31) / 32, cbu = (NU + 31) / 32;    // combine sub-grids

    // ---- layer 0 ----
    agg2_kernel<<<gi2 + gu2, 256, 0, stream>>>(hu0b, hi0b, rs_i, csr_u2i, agg_i, gi2,
                                               rs_u, csr_i2u, agg_u);
    conv2_kernel<<<ci + cu, 256, 0, stream>>>(
        agg_i, hi0b, wt_l0_i, bn01 + 0, bs01 + 0, hi_b, ci,
        agg_u, hu0b, wt_l0_u, bn01 + 128, bs01 + 128, hu_b);
    // ---- layer 1 ----
    agg2_kernel<<<gi2 + gu2, 256, 0, stream>>>(hu_b, hi_b, rs_i, csr_u2i, agg_i, gi2,
                                               rs_u, csr_i2u, agg_u);
    conv2_kernel<<<ci + cu, 256, 0, stream>>>(
        agg_i, hi_b, wt_l1_i, bn01 + 256, bs01 + 256, hi_a, ci,
        agg_u, hu_b, wt_l1_u, bn01 + 384, bs01 + 384, hu_a);
    // ---- layer 2: pre-project (mean(h)@W = mean(h@W)), 64-dim agg, combine ----
    proj2_kernel<<<ci + cu, 256, 0, stream>>>(hi_a, wt_pi, proj_i, ci,
                                              hu_a, wt_pu, proj_u);
    agg64_kernel<<<gi64 + gu64, 256, 0, stream>>>(proj_u, proj_i, rs_i, csr_u2i,
                                                  agg64_i, gi64,
                                                  rs_u, csr_i2u, agg64_u);
    combine2_kernel<<<cbi + cbu, 256, 0, stream>>>(
        agg64_i, proj_i, bn2, bs2, out_hi, hi2b, cbi,
        agg64_u, proj_u, out_hu, hu2b);

    // ---- cosine scores (pos + neg in one launch) ----
    score2_kernel<<<dim3((NP + 31) / 32, 2), 256, 0, stream>>>(
        hu2b, hi2b, pos_u, pos_i, out_pos, neg_u, neg_i, out_neg, NP);
}

// Round 17
// 529.905 us; speedup vs baseline: 1.5167x; 1.0022x over previous
//
#include <hip/hip_runtime.h>
#include <hip/hip_bf16.h>

// Problem constants (from reference)
#define NU 100000
#define NI 50000
#define NE 1000000
#define NP 500000
// D_IN = D_HID = 128, D_OUT = 64

typedef unsigned short u16;
typedef unsigned int u32;
typedef __attribute__((ext_vector_type(8))) short short8;   // 8 bf16 (4 VGPRs)
typedef __attribute__((ext_vector_type(4))) float f32x4;

static __device__ __forceinline__ u16 f2bf(float f) {
    union { float f; u32 u; } x; x.f = f;
    u32 r = x.u + 0x7fff + ((x.u >> 16) & 1);   // round-to-nearest-even
    return (u16)(r >> 16);
}
static __device__ __forceinline__ float bf2f(u16 h) {
    union { u32 u; float f; } x; x.u = ((u32)h) << 16;
    return x.f;
}

// NOTE (r15 lesson): all feature tables are LINEAR [N][128]/[N][64] bf16.
// Dim-sliced layouts (32B rows) regressed 2.3x: random gathers must keep
// row granularity >= cache line. agg2 at r14 layout is ~at the LLC
// random-gather floor (FETCH ~ 8-XCD-replicated table).

// ---------------- f32 -> bf16 table conversion ----------------
__global__ __launch_bounds__(256) void cvt_kernel(const float* __restrict__ in,
                                                  u16* __restrict__ out, int n8) {
    int i = blockIdx.x * blockDim.x + threadIdx.x;
    if (i >= n8) return;
    float4 a = ((const float4*)in)[2 * i];
    float4 b = ((const float4*)in)[2 * i + 1];
    ushort4 lo = {f2bf(a.x), f2bf(a.y), f2bf(a.z), f2bf(a.w)};
    ushort4 hi = {f2bf(b.x), f2bf(b.y), f2bf(b.z), f2bf(b.w)};
    ((ushort4*)out)[2 * i]     = lo;
    ((ushort4*)out)[2 * i + 1] = hi;
}

// ---------------- weight transposes in one launch ----------------
// wt layout (u16): 4 x (128x256) layers 0/1 [n][k], then wt_pu (128x128) and
// wt_pi (128x128) for the layer-2 pre-projection:
//   wt_pu: cols 0..63 = Wn2_i (items' neighbor proj), 64..127 = Ws2_u (users' self)
//   wt_pi: cols 0..63 = Wn2_u (users' neighbor proj), 64..127 = Ws2_i (items' self)
__global__ void wtrans_all_kernel(const float* __restrict__ Wn01,
                                  const float* __restrict__ Ws01,
                                  const float* __restrict__ Wn2,
                                  const float* __restrict__ Ws2,
                                  u16* __restrict__ wt) {
    int x = blockIdx.x;            // 0..767
    int k = threadIdx.x;           // 0..127
    if (x < 512) {
        int m = x >> 7, n = x & 127;
        const float* Wn = Wn01 + m * 16384;
        const float* Ws = Ws01 + m * 16384;
        size_t o = (size_t)m * 128 * 256;
        wt[o + (size_t)n * 256 + k]       = f2bf(Wn[(size_t)k * 128 + n]);
        wt[o + (size_t)n * 256 + 128 + k] = f2bf(Ws[(size_t)k * 128 + n]);
    } else {
        int m = (x - 512) >> 7;    // 0 = pu, 1 = pi
        int n = (x - 512) & 127;
        size_t o = 131072 + (size_t)m * 16384;
        float v;
        if (m == 0) v = (n < 64) ? Wn2[(size_t)k * 64 + n]
                                 : Ws2[8192 + (size_t)k * 64 + (n - 64)];
        else        v = (n < 64) ? Wn2[8192 + (size_t)k * 64 + n]
                                 : Ws2[(size_t)k * 64 + (n - 64)];
        wt[o + (size_t)n * 128 + k] = f2bf(v);
    }
}

// ---------------- CSR build ----------------

__global__ void hist2_kernel(const int* __restrict__ d0, int* __restrict__ deg0,
                             int* __restrict__ rank0,
                             const int* __restrict__ d1, int* __restrict__ deg1,
                             int* __restrict__ rank1, int E) {
    int e = blockIdx.x * blockDim.x + threadIdx.x;
    if (e >= E) return;
    if (blockIdx.y == 0) {
        int d = __builtin_nontemporal_load(&d0[e]);
        int r = atomicAdd(&deg0[d], 1);
        __builtin_nontemporal_store(r, &rank0[e]);
    } else {
        int d = __builtin_nontemporal_load(&d1[e]);
        int r = atomicAdd(&deg1[d], 1);
        __builtin_nontemporal_store(r, &rank1[e]);
    }
}

__global__ void scan2_local_kernel(const int* __restrict__ in0, int* __restrict__ out0,
                                   int* __restrict__ bsum0, int n0,
                                   const int* __restrict__ in1, int* __restrict__ out1,
                                   int* __restrict__ bsum1, int n1) {
    const int* in; int *out, *bsum; int n;
    if (blockIdx.y == 0) { in = in0; out = out0; bsum = bsum0; n = n0; }
    else                 { in = in1; out = out1; bsum = bsum1; n = n1; }
    __shared__ int s[1024];
    int i = blockIdx.x * 1024 + threadIdx.x;
    int v = (i < n) ? in[i] : 0;
    s[threadIdx.x] = v;
    __syncthreads();
    for (int off = 1; off < 1024; off <<= 1) {
        int t = (threadIdx.x >= off) ? s[threadIdx.x - off] : 0;
        __syncthreads();
        s[threadIdx.x] += t;
        __syncthreads();
    }
    if (i < n) out[i] = s[threadIdx.x] - v;   // exclusive within block
    if (threadIdx.x == 1023) bsum[blockIdx.x] = s[1023];
}

__global__ void scan2_bsum_kernel(int* b0, int nb0, int* b1, int nb1) {
    int* bsum; int nb;
    if (blockIdx.y == 0) { bsum = b0; nb = nb0; }
    else                 { bsum = b1; nb = nb1; }
    __shared__ int s[1024];
    int v = ((int)threadIdx.x < nb) ? bsum[threadIdx.x] : 0;
    s[threadIdx.x] = v;
    __syncthreads();
    for (int off = 1; off < 1024; off <<= 1) {
        int t = (threadIdx.x >= off) ? s[threadIdx.x - off] : 0;
        __syncthreads();
        s[threadIdx.x] += t;
        __syncthreads();
    }
    if ((int)threadIdx.x < nb) bsum[threadIdx.x] = s[threadIdx.x] - v;  // exclusive
}

__global__ void scan2_finalize_kernel(int* __restrict__ rs0, const int* __restrict__ b0,
                                      int n0, int* __restrict__ rs1,
                                      const int* __restrict__ b1, int n1, int E) {
    int* rs; const int* bsum; int n;
    if (blockIdx.y == 0) { rs = rs0; bsum = b0; n = n0; }
    else                 { rs = rs1; bsum = b1; n = n1; }
    int i = blockIdx.x * 1024 + threadIdx.x;
    if (i < n) rs[i] += bsum[blockIdx.x];
    if (i == 0) rs[n] = E;
}

// single-pass atomic-free fill: csr[rs[d] + rank[e]] = src[e].
__global__ void fill2_kernel(const int* __restrict__ s0, const int* __restrict__ d0,
                             const int* __restrict__ r0, const int* __restrict__ rs0,
                             int* __restrict__ csr0,
                             const int* __restrict__ s1, const int* __restrict__ d1,
                             const int* __restrict__ r1, const int* __restrict__ rs1,
                             int* __restrict__ csr1, int E) {
    const int *src, *dst, *rk, *rs; int* csr;
    if (blockIdx.y == 0) { src = s0; dst = d0; rk = r0; rs = rs0; csr = csr0; }
    else                 { src = s1; dst = d1; rk = r1; rs = rs1; csr = csr1; }
    int e = blockIdx.x * blockDim.x + threadIdx.x;
    if (e >= E) return;
    int d = __builtin_nontemporal_load(&dst[e]);
    int r = __builtin_nontemporal_load(&rk[e]);
    int s = __builtin_nontemporal_load(&src[e]);
    csr[rs[d] + r] = s;
}

// ---------------- mean aggregation, items + users in ONE launch ----------------
// r14 version (at LLC random-gather floor). 16 lanes own one node (8 dims/lane
// = full 128-dim row; no end shuffle, direct store); 4-deep edge unroll.
__global__ __launch_bounds__(256) void agg2_kernel(
    const u16* __restrict__ hu, const u16* __restrict__ hi,
    const int* __restrict__ rs_i, const int* __restrict__ csr_i,
    u16* __restrict__ out_i, int gi2,
    const int* __restrict__ rs_u, const int* __restrict__ csr_u,
    u16* __restrict__ out_u) {
    const u16* hsrc; const int *rs, *csr; u16* out; int T, t;
    int bx = blockIdx.x;
    int grp = threadIdx.x >> 4;        // 0..15 node groups per block
    int lr  = threadIdx.x & 15;        // dims lr*8 .. lr*8+7
    if (bx < gi2) { hsrc = hu; rs = rs_i; csr = csr_i; out = out_i; T = NI;
                    t = bx * 16 + grp; }
    else          { hsrc = hi; rs = rs_u; csr = csr_u; out = out_u; T = NU;
                    t = (bx - gi2) * 16 + grp; }
    if (t >= T) return;
    int e0 = rs[t], e1 = rs[t + 1];
    float acc[8] = {};
    int e = e0;
    for (; e + 3 < e1; e += 4) {       // 4 gathers in flight per group
        int s0 = __builtin_nontemporal_load(&csr[e]);
        int s1 = __builtin_nontemporal_load(&csr[e + 1]);
        int s2 = __builtin_nontemporal_load(&csr[e + 2]);
        int s3 = __builtin_nontemporal_load(&csr[e + 3]);
        short8 v0 = *(const short8*)&hsrc[(size_t)s0 * 128 + (lr << 3)];
        short8 v1 = *(const short8*)&hsrc[(size_t)s1 * 128 + (lr << 3)];
        short8 v2 = *(const short8*)&hsrc[(size_t)s2 * 128 + (lr << 3)];
        short8 v3 = *(const short8*)&hsrc[(size_t)s3 * 128 + (lr << 3)];
        #pragma unroll
        for (int q = 0; q < 8; ++q)
            acc[q] += (bf2f((u16)v0[q]) + bf2f((u16)v1[q])) +
                      (bf2f((u16)v2[q]) + bf2f((u16)v3[q]));
    }
    for (; e < e1; ++e) {
        int s0 = __builtin_nontemporal_load(&csr[e]);
        short8 v0 = *(const short8*)&hsrc[(size_t)s0 * 128 + (lr << 3)];
        #pragma unroll
        for (int q = 0; q < 8; ++q) acc[q] += bf2f((u16)v0[q]);
    }
    float inv = (e1 > e0) ? 1.f / (float)(e1 - e0) : 0.f;
    short8 o;
    #pragma unroll
    for (int q = 0; q < 8; ++q) o[q] = (short)f2bf(acc[q] * inv);
    __builtin_nontemporal_store(o, (short8*)&out[(size_t)t * 128 + (lr << 3)]);
}

// ---------------- layer-2: 64-dim aggregation over projected tables ----------------
// Gathers only cols 0..63 (first 128B) of the [*,128] projected rows.
__global__ __launch_bounds__(256) void agg64_kernel(
    const u16* __restrict__ pu, const u16* __restrict__ pi,
    const int* __restrict__ rs_i, const int* __restrict__ csr_i,
    u16* __restrict__ out_i, int gi64,
    const int* __restrict__ rs_u, const int* __restrict__ csr_u,
    u16* __restrict__ out_u) {
    const u16* hsrc; const int *rs, *csr; u16* out; int T, t;
    int bx = blockIdx.x;
    int grp = threadIdx.x >> 3;        // 0..31 node groups per block
    int lr  = threadIdx.x & 7;         // dims lr*8 .. lr*8+7
    if (bx < gi64) { hsrc = pu; rs = rs_i; csr = csr_i; out = out_i; T = NI;
                     t = bx * 32 + grp; }
    else           { hsrc = pi; rs = rs_u; csr = csr_u; out = out_u; T = NU;
                     t = (bx - gi64) * 32 + grp; }
    if (t >= T) return;
    int e0 = rs[t], e1 = rs[t + 1];
    float acc[8] = {};
    int e = e0;
    for (; e + 3 < e1; e += 4) {
        int s0 = __builtin_nontemporal_load(&csr[e]);
        int s1 = __builtin_nontemporal_load(&csr[e + 1]);
        int s2 = __builtin_nontemporal_load(&csr[e + 2]);
        int s3 = __builtin_nontemporal_load(&csr[e + 3]);
        short8 v0 = *(const short8*)&hsrc[(size_t)s0 * 128 + (lr << 3)];
        short8 v1 = *(const short8*)&hsrc[(size_t)s1 * 128 + (lr << 3)];
        short8 v2 = *(const short8*)&hsrc[(size_t)s2 * 128 + (lr << 3)];
        short8 v3 = *(const short8*)&hsrc[(size_t)s3 * 128 + (lr << 3)];
        #pragma unroll
        for (int q = 0; q < 8; ++q)
            acc[q] += (bf2f((u16)v0[q]) + bf2f((u16)v1[q])) +
                      (bf2f((u16)v2[q]) + bf2f((u16)v3[q]));
    }
    for (; e < e1; ++e) {
        int s0 = __builtin_nontemporal_load(&csr[e]);
        short8 v0 = *(const short8*)&hsrc[(size_t)s0 * 128 + (lr << 3)];
        #pragma unroll
        for (int q = 0; q < 8; ++q) acc[q] += bf2f((u16)v0[q]);
    }
    float inv = (e1 > e0) ? 1.f / (float)(e1 - e0) : 0.f;
    short8 o;
    #pragma unroll
    for (int q = 0; q < 8; ++q) o[q] = (short)f2bf(acc[q] * inv);
    __builtin_nontemporal_store(o, (short8*)&out[(size_t)t * 64 + (lr << 3)]);
}

// ---------------- conv via MFMA (layers 0/1), items + users in ONE launch ----
// z = [hn|hd] @ Wt^T + bn + bs; relu; row L2-norm. 4 waves, 32-row tile.
// TM=32 (was 64): LDS 17.5KB -> 8 blocks/CU = 100% wave occupancy (r8/r14
// showed these kernels latency-bound at 50% occupancy, MfmaUtil ~4%).
__global__ __launch_bounds__(256) void conv2_kernel(
    const u16* __restrict__ hn_i, const u16* __restrict__ hd_i,
    const u16* __restrict__ wt_i, const float* __restrict__ bn_i,
    const float* __restrict__ bs_i, u16* __restrict__ outb_i, int ci,
    const u16* __restrict__ hn_u, const u16* __restrict__ hd_u,
    const u16* __restrict__ wt_u, const float* __restrict__ bn_u,
    const float* __restrict__ bs_u, u16* __restrict__ outb_u)
{
    constexpr int NF   = 2;
    constexpr int FSTR = 132;
    __shared__ u16 smA[32 * 264];                  // 16896 B, reused as f32 out
    __shared__ float psum[4][32];
    __shared__ float sinv[32];
    float* smF = (float*)smA;

    const u16 *hn, *hd, *Wt; const float *bn, *bs; u16* outb; int T, t0;
    if ((int)blockIdx.x < ci) {
        hn = hn_i; hd = hd_i; Wt = wt_i; bn = bn_i; bs = bs_i;
        outb = outb_i; T = NI; t0 = blockIdx.x * 32;
    } else {
        hn = hn_u; hd = hd_u; Wt = wt_u; bn = bn_u; bs = bs_u;
        outb = outb_u; T = NU; t0 = (blockIdx.x - ci) * 32;
    }

    const int tid  = threadIdx.x;
    const int wave = tid >> 6;
    const int lane = tid & 63;
    const int lr   = lane & 15;
    const int lg   = lane >> 4;

    // stage A = [hn | hd]: 32 rows x 32 chunks of 16B
    #pragma unroll
    for (int i = 0; i < 4; ++i) {
        int lin = i * 256 + tid;
        int row = lin >> 5;
        int q   = lin & 31;
        int t   = t0 + row; if (t >= T) t = T - 1;
        const u16* srcp = (q < 16) ? &hn[(size_t)t * 128 + (q << 3)]
                                   : &hd[(size_t)t * 128 + ((q - 16) << 3)];
        *(short8*)&smA[row * 264 + (q << 3)] = *(const short8*)srcp;
    }
    __syncthreads();

    const u16* wp[NF];
    float bias[NF];
    #pragma unroll
    for (int ni = 0; ni < NF; ++ni) {
        int col = wave * 32 + ni * 16 + lr;
        wp[ni] = Wt + (size_t)col * 256;
        bias[ni] = bn[col] + bs[col];
    }

    f32x4 acc[2][NF];
    #pragma unroll
    for (int mi = 0; mi < 2; ++mi)
        #pragma unroll
        for (int ni = 0; ni < NF; ++ni)
            acc[mi][ni] = (f32x4){0.f, 0.f, 0.f, 0.f};

    #pragma unroll
    for (int ks = 0; ks < 8; ++ks) {
        const int kb = ks * 32 + (lg << 3);
        short8 b[NF];
        #pragma unroll
        for (int ni = 0; ni < NF; ++ni) b[ni] = *(const short8*)&wp[ni][kb];
        #pragma unroll
        for (int mi = 0; mi < 2; ++mi) {
            short8 a = *(const short8*)&smA[(mi * 16 + lr) * 264 + kb];
            #pragma unroll
            for (int ni = 0; ni < NF; ++ni)
                acc[mi][ni] = __builtin_amdgcn_mfma_f32_16x16x32_bf16(a, b[ni], acc[mi][ni], 0, 0, 0);
        }
    }
    __syncthreads();

    float rsum[2][4];
    #pragma unroll
    for (int mi = 0; mi < 2; ++mi) {
        #pragma unroll
        for (int j = 0; j < 4; ++j) {
            int rowg = mi * 16 + lg * 4 + j;
            float s = 0.f;
            #pragma unroll
            for (int ni = 0; ni < NF; ++ni) {
                float z = fmaxf(acc[mi][ni][j] + bias[ni], 0.f);
                int colg = wave * 32 + ni * 16 + lr;
                smF[rowg * FSTR + colg] = z;
                s = fmaf(z, z, s);
            }
            rsum[mi][j] = s;
        }
    }
    #pragma unroll
    for (int m = 1; m < 16; m <<= 1)
        #pragma unroll
        for (int mi = 0; mi < 2; ++mi)
            #pragma unroll
            for (int j = 0; j < 4; ++j)
                rsum[mi][j] += __shfl_xor(rsum[mi][j], m);
    if (lr == 0) {
        #pragma unroll
        for (int mi = 0; mi < 2; ++mi)
            #pragma unroll
            for (int j = 0; j < 4; ++j)
                psum[wave][mi * 16 + lg * 4 + j] = rsum[mi][j];
    }
    __syncthreads();
    if (tid < 32) {
        float n2 = psum[0][tid] + psum[1][tid] + psum[2][tid] + psum[3][tid];
        sinv[tid] = 1.f / fmaxf(sqrtf(n2), 1e-12f);
    }
    __syncthreads();

    // coalesced readback + store: 32 rows x 16 chunks of 8 cols
    #pragma unroll
    for (int i = 0; i < 2; ++i) {
        int lin = i * 256 + tid;
        int row = lin >> 4, g = lin & 15;
        int t = t0 + row;
        if (t < T) {
            float inv = sinv[row];
            float4 z0 = *(float4*)&smF[row * FSTR + g * 8];
            float4 z1 = *(float4*)&smF[row * FSTR + g * 8 + 4];
            short8 ob = {(short)f2bf(z0.x * inv), (short)f2bf(z0.y * inv),
                         (short)f2bf(z0.z * inv), (short)f2bf(z0.w * inv),
                         (short)f2bf(z1.x * inv), (short)f2bf(z1.y * inv),
                         (short)f2bf(z1.z * inv), (short)f2bf(z1.w * inv)};
            *(short8*)&outb[(size_t)t * 128 + g * 8] = ob;
        }
    }
}

// ---------------- layer-2 pre-projection GEMM: p = h @ [Wn|Ws] (128->128) ----
// No bias/relu/norm. TM=32 tile (occupancy, same as conv2).
__global__ __launch_bounds__(256) void proj2_kernel(
    const u16* __restrict__ A_i, const u16* __restrict__ wt_pi,
    u16* __restrict__ out_i, int ci,
    const u16* __restrict__ A_u, const u16* __restrict__ wt_pu,
    u16* __restrict__ out_u)
{
    constexpr int NF = 2;
    constexpr int FSTR = 132;
    __shared__ float smF[32 * FSTR];               // 16896 B; low half doubles as A
    u16* smA = (u16*)smF;                          // 32 x 136 u16 = 8704 B

    const u16 *A, *Wt; u16* outb; int T, t0;
    if ((int)blockIdx.x < ci) {
        A = A_i; Wt = wt_pi; outb = out_i; T = NI; t0 = blockIdx.x * 32;
    } else {
        A = A_u; Wt = wt_pu; outb = out_u; T = NU; t0 = (blockIdx.x - ci) * 32;
    }

    const int tid  = threadIdx.x;
    const int wave = tid >> 6;
    const int lane = tid & 63;
    const int lr   = lane & 15;
    const int lg   = lane >> 4;

    // stage A: 32 rows x 16 chunks of 16B, stride 136
    #pragma unroll
    for (int i = 0; i < 2; ++i) {
        int lin = i * 256 + tid;
        int row = lin >> 4;
        int q   = lin & 15;
        int t   = t0 + row; if (t >= T) t = T - 1;
        *(short8*)&smA[row * 136 + (q << 3)] =
            *(const short8*)&A[(size_t)t * 128 + (q << 3)];
    }
    __syncthreads();

    const u16* wp[NF];
    #pragma unroll
    for (int ni = 0; ni < NF; ++ni) {
        int col = wave * 32 + ni * 16 + lr;
        wp[ni] = Wt + (size_t)col * 128;
    }

    f32x4 acc[2][NF];
    #pragma unroll
    for (int mi = 0; mi < 2; ++mi)
        #pragma unroll
        for (int ni = 0; ni < NF; ++ni)
            acc[mi][ni] = (f32x4){0.f, 0.f, 0.f, 0.f};

    #pragma unroll
    for (int ks = 0; ks < 4; ++ks) {
        const int kb = ks * 32 + (lg << 3);
        short8 b[NF];
        #pragma unroll
        for (int ni = 0; ni < NF; ++ni) b[ni] = *(const short8*)&wp[ni][kb];
        #pragma unroll
        for (int mi = 0; mi < 2; ++mi) {
            short8 a = *(const short8*)&smA[(mi * 16 + lr) * 136 + kb];
            #pragma unroll
            for (int ni = 0; ni < NF; ++ni)
                acc[mi][ni] = __builtin_amdgcn_mfma_f32_16x16x32_bf16(a, b[ni], acc[mi][ni], 0, 0, 0);
        }
    }
    __syncthreads();

    // acc -> LDS transpose buffer (no bias/relu/norm)
    #pragma unroll
    for (int mi = 0; mi < 2; ++mi)
        #pragma unroll
        for (int j = 0; j < 4; ++j) {
            int rowg = mi * 16 + lg * 4 + j;
            #pragma unroll
            for (int ni = 0; ni < NF; ++ni)
                smF[rowg * FSTR + wave * 32 + ni * 16 + lr] = acc[mi][ni][j];
        }
    __syncthreads();

    #pragma unroll
    for (int i = 0; i < 2; ++i) {
        int lin = i * 256 + tid;
        int row = lin >> 4, g = lin & 15;
        int t = t0 + row;
        if (t < T) {
            float4 z0 = *(float4*)&smF[row * FSTR + g * 8];
            float4 z1 = *(float4*)&smF[row * FSTR + g * 8 + 4];
            short8 ob = {(short)f2bf(z0.x), (short)f2bf(z0.y),
                         (short)f2bf(z0.z), (short)f2bf(z0.w),
                         (short)f2bf(z1.x), (short)f2bf(z1.y),
                         (short)f2bf(z1.z), (short)f2bf(z1.w)};
            *(short8*)&outb[(size_t)t * 128 + g * 8] = ob;
        }
    }
}

// ---------------- layer-2 combine: z = agg64 + self + biases; relu; L2-norm ----
// 32 rows x 8 lanes per block; lane owns 8 dims. Writes f32 d_out + bf16 copy.
__global__ __launch_bounds__(256) void combine2_kernel(
    const u16* __restrict__ agg_i, const u16* __restrict__ proj_i,
    const float* __restrict__ bn2, const float* __restrict__ bs2,
    float* __restrict__ outf_i, u16* __restrict__ outb_i, int cbi,
    const u16* __restrict__ agg_u, const u16* __restrict__ proj_u,
    float* __restrict__ outf_u, u16* __restrict__ outb_u)
{
    const u16 *agg, *proj; const float *bn, *bs; float* outf; u16* outb; int T, r0;
    if ((int)blockIdx.x < cbi) {
        agg = agg_i; proj = proj_i; bn = bn2;      bs = bs2;
        outf = outf_i; outb = outb_i; T = NI; r0 = blockIdx.x * 32;
    } else {
        agg = agg_u; proj = proj_u; bn = bn2 + 64; bs = bs2 + 64;
        outf = outf_u; outb = outb_u; T = NU; r0 = (blockIdx.x - cbi) * 32;
    }
    int g = threadIdx.x >> 3, l = threadIdx.x & 7;
    int r = r0 + g;
    if (r >= T) return;
    short8 va = *(const short8*)&agg[(size_t)r * 64 + (l << 3)];
    short8 vs = *(const short8*)&proj[(size_t)r * 128 + 64 + (l << 3)];
    float z[8];
    float s = 0.f;
    #pragma unroll
    for (int q = 0; q < 8; ++q) {
        float v = bf2f((u16)va[q]) + bf2f((u16)vs[q]) + bn[l * 8 + q] + bs[l * 8 + q];
        v = fmaxf(v, 0.f);
        z[q] = v;
        s = fmaf(v, v, s);
    }
    s += __shfl_xor(s, 1);
    s += __shfl_xor(s, 2);
    s += __shfl_xor(s, 4);
    float inv = 1.f / fmaxf(sqrtf(s), 1e-12f);
    short8 ob;
    float4 o0, o1;
    o0.x = z[0] * inv; o0.y = z[1] * inv; o0.z = z[2] * inv; o0.w = z[3] * inv;
    o1.x = z[4] * inv; o1.y = z[5] * inv; o1.z = z[6] * inv; o1.w = z[7] * inv;
    #pragma unroll
    for (int q = 0; q < 8; ++q) ob[q] = (short)f2bf(z[q] * inv);
    *(short8*)&outb[(size_t)r * 64 + (l << 3)] = ob;
    *(float4*)&outf[(size_t)r * 64 + (l << 3)]     = o0;
    *(float4*)&outf[(size_t)r * 64 + (l << 3) + 4] = o1;
}

// ---------------- cosine scores, pos + neg in ONE launch ----------------
__global__ __launch_bounds__(256) void score2_kernel(
    const u16* __restrict__ hu, const u16* __restrict__ hi,
    const int* __restrict__ pu0, const int* __restrict__ pi0, float* __restrict__ out0,
    const int* __restrict__ pu1, const int* __restrict__ pi1, float* __restrict__ out1,
    int P) {
    const int *pu, *pi; float* out;
    if (blockIdx.y == 0) { pu = pu0; pi = pi0; out = out0; }
    else                 { pu = pu1; pi = pi1; out = out1; }
    int g = threadIdx.x >> 3, l = threadIdx.x & 7;
    int p = blockIdx.x * 32 + g;
    if (p >= P) return;
    int u = __builtin_nontemporal_load(&pu[p]);
    int it = __builtin_nontemporal_load(&pi[p]);
    short8 a = *(const short8*)&hu[(size_t)u * 64 + (l << 3)];
    short8 b = *(const short8*)&hi[(size_t)it * 64 + (l << 3)];
    float d = 0.f, na = 0.f, nb = 0.f;
    #pragma unroll
    for (int q = 0; q < 8; ++q) {
        float x = bf2f((u16)a[q]), y = bf2f((u16)b[q]);
        d  = fmaf(x, y, d);
        na = fmaf(x, x, na);
        nb = fmaf(y, y, nb);
    }
    #pragma unroll
    for (int m = 1; m < 8; m <<= 1) {
        d  += __shfl_xor(d, m);
        na += __shfl_xor(na, m);
        nb += __shfl_xor(nb, m);
    }
    if (l == 0) out[p] = d / (fmaxf(sqrtf(na), 1e-12f) * fmaxf(sqrtf(nb), 1e-12f));
}

// ---------------- host ----------------

extern "C" void kernel_launch(void* const* d_in, const int* in_sizes, int n_in,
                              void* d_out, int out_size, void* d_ws, size_t ws_size,
                              hipStream_t stream) {
    const float* h_user = (const float*)d_in[0];
    const float* h_item = (const float*)d_in[1];
    const float* Wn01   = (const float*)d_in[2];
    const float* bn01   = (const float*)d_in[3];
    const float* Ws01   = (const float*)d_in[4];
    const float* bs01   = (const float*)d_in[5];
    const float* Wn2    = (const float*)d_in[6];
    const float* bn2    = (const float*)d_in[7];
    const float* Ws2    = (const float*)d_in[8];
    const float* bs2    = (const float*)d_in[9];
    const int* u2i_src  = (const int*)d_in[10];
    const int* u2i_dst  = (const int*)d_in[11];
    const int* i2u_src  = (const int*)d_in[12];
    const int* i2u_dst  = (const int*)d_in[13];
    const int* pos_u    = (const int*)d_in[14];
    const int* pos_i    = (const int*)d_in[15];
    const int* neg_u    = (const int*)d_in[16];
    const int* neg_i    = (const int*)d_in[17];

    float* out = (float*)d_out;
    float* out_hu = out;                       // [NU,64]
    float* out_hi = out + (size_t)NU * 64;     // [NI,64]
    float* out_pos = out + (size_t)NU * 64 + (size_t)NI * 64;
    float* out_neg = out_pos + NP;

    // workspace layout
    char* ws = (char*)d_ws;
    size_t off = 0;
    auto alloc = [&](size_t bytes) -> void* {
        void* p = ws + off;
        off = (off + bytes + 255) & ~(size_t)255;
        return p;
    };
    u16* hu0b = (u16*)alloc((size_t)NU * 128 * 2);   // bf16 copies of inputs
    u16* hi0b = (u16*)alloc((size_t)NI * 128 * 2);
    u16* hu_b = (u16*)alloc((size_t)NU * 128 * 2);   // layer-0 out; layer-2 proj_u reuse
    u16* hi_b = (u16*)alloc((size_t)NI * 128 * 2);   // layer-0 out; layer-2 proj_i reuse
    u16* hu_a = (u16*)alloc((size_t)NU * 128 * 2);   // layer-1 out
    u16* hi_a = (u16*)alloc((size_t)NI * 128 * 2);
    u16* agg_i = (u16*)alloc((size_t)NI * 128 * 2);  // agg outputs (bf16)
    u16* agg_u = (u16*)alloc((size_t)NU * 128 * 2);
    u16* hu2b = (u16*)alloc((size_t)NU * 64 * 2);    // final embeddings (bf16, scores)
    u16* hi2b = (u16*)alloc((size_t)NI * 64 * 2);
    u16* wt_all = (u16*)alloc((size_t)(4 * 128 * 256 + 2 * 128 * 128) * 2);
    u16* wt_l0_i = wt_all;                 // each 128x256
    u16* wt_l0_u = wt_all + 32768;
    u16* wt_l1_i = wt_all + 65536;
    u16* wt_l1_u = wt_all + 98304;
    u16* wt_pu   = wt_all + 131072;        // 128x128 [Wn2_i | Ws2_u]
    u16* wt_pi   = wt_all + 147456;        // 128x128 [Wn2_u | Ws2_i]
    int* csr_u2i = (int*)alloc((size_t)NE * 4);
    int* csr_i2u = (int*)alloc((size_t)NE * 4);
    int* rs_i   = (int*)alloc((size_t)(NI + 1) * 4);
    int* rs_u   = (int*)alloc((size_t)(NU + 1) * 4);
    int* deg    = (int*)alloc((size_t)(NI + NU) * 4);   // deg_i | deg_u
    int* bsum_i = (int*)alloc(1024 * 4);
    int* bsum_u = (int*)alloc(1024 * 4);
    int* deg_i = deg, *deg_u = deg + NI;
    // rank arrays alias the (not-yet-live) agg buffers (hist2/fill2 complete
    // before the first agg2 writes them; single stream = sequential).
    int* rank_i = (int*)agg_i;
    int* rank_u = (int*)agg_u;
    // layer-2: proj buffers reuse the dead layer-0 outputs; agg64 reuses agg bufs
    u16* proj_u = hu_b;
    u16* proj_i = hi_b;
    u16* agg64_i = agg_i;
    u16* agg64_u = agg_u;
    (void)ws_size; (void)in_sizes; (void)n_in; (void)out_size;

    const int eblocks = (NE + 255) / 256;

    // ---- bf16 copies of input features + all transposed bf16 weights ----
    cvt_kernel<<<(NU * 128 / 8 + 255) / 256, 256, 0, stream>>>(h_user, hu0b, NU * 128 / 8);
    cvt_kernel<<<(NI * 128 / 8 + 255) / 256, 256, 0, stream>>>(h_item, hi0b, NI * 128 / 8);
    wtrans_all_kernel<<<768, 128, 0, stream>>>(Wn01, Ws01, Wn2, Ws2, wt_all);

    // ---- CSR build (both directions, rank-based single-pass fill) ----
    hipMemsetAsync(deg, 0, (size_t)(NI + NU) * 4, stream);
    hist2_kernel<<<dim3(eblocks, 2), 256, 0, stream>>>(u2i_dst, deg_i, rank_i,
                                                       i2u_dst, deg_u, rank_u, NE);
    const int nb_i = (NI + 1023) / 1024, nb_u = (NU + 1023) / 1024;
    const int nb_max = (nb_i > nb_u) ? nb_i : nb_u;
    scan2_local_kernel<<<dim3(nb_max, 2), 1024, 0, stream>>>(
        deg_i, rs_i, bsum_i, NI, deg_u, rs_u, bsum_u, NU);
    scan2_bsum_kernel<<<dim3(1, 2), 1024, 0, stream>>>(bsum_i, nb_i, bsum_u, nb_u);
    scan2_finalize_kernel<<<dim3(nb_max, 2), 1024, 0, stream>>>(
        rs_i, bsum_i, NI, rs_u, bsum_u, NU, NE);
    fill2_kernel<<<dim3(eblocks, 2), 256, 0, stream>>>(
        u2i_src, u2i_dst, rank_i, rs_i, csr_u2i,
        i2u_src, i2u_dst, rank_u, rs_u, csr_i2u, NE);

    const int gi2 = (NI + 15) / 16, gu2 = (NU + 15) / 16;    // agg2 sub-grids
    const int gi64 = (NI + 31) / 32, gu64 = (NU + 31) / 32;  // agg64 sub-grids
    const int ci = (NI + 31) / 32, cu = (NU + 31) / 32;      // conv/proj sub-grids (TM=32)
    const int cbi = (NI + 31) / 32, cbu = (NU + 31) / 32;    // combine sub-grids

    // ---- layer 0 ----
    agg2_kernel<<<gi2 + gu2, 256, 0, stream>>>(hu0b, hi0b, rs_i, csr_u2i, agg_i, gi2,
                                               rs_u, csr_i2u, agg_u);
    conv2_kernel<<<ci + cu, 256, 0, stream>>>(
        agg_i, hi0b, wt_l0_i, bn01 + 0, bs01 + 0, hi_b, ci,
        agg_u, hu0b, wt_l0_u, bn01 + 128, bs01 + 128, hu_b);
    // ---- layer 1 ----
    agg2_kernel<<<gi2 + gu2, 256, 0, stream>>>(hu_b, hi_b, rs_i, csr_u2i, agg_i, gi2,
                                               rs_u, csr_i2u, agg_u);
    conv2_kernel<<<ci + cu, 256, 0, stream>>>(
        agg_i, hi_b, wt_l1_i, bn01 + 256, bs01 + 256, hi_a, ci,
        agg_u, hu_b, wt_l1_u, bn01 + 384, bs01 + 384, hu_a);
    // ---- layer 2: pre-project (mean(h)@W = mean(h@W)), 64-dim agg, combine ----
    proj2_kernel<<<ci + cu, 256, 0, stream>>>(hi_a, wt_pi, proj_i, ci,
                                              hu_a, wt_pu, proj_u);
    agg64_kernel<<<gi64 + gu64, 256, 0, stream>>>(proj_u, proj_i, rs_i, csr_u2i,
                                                  agg64_i, gi64,
                                                  rs_u, csr_i2u, agg64_u);
    combine2_kernel<<<cbi + cbu, 256, 0, stream>>>(
        agg64_i, proj_i, bn2, bs2, out_hi, hi2b, cbi,
        agg64_u, proj_u, out_hu, hu2b);

    // ---- cosine scores (pos + neg in one launch) ----
    score2_kernel<<<dim3((NP + 31) / 32, 2), 256, 0, stream>>>(
        hu2b, hi2b, pos_u, pos_i, out_pos, neg_u, neg_i, out_neg, NP);
}

// Round 18
// 492.430 us; speedup vs baseline: 1.6321x; 1.0761x over previous
//
#include <hip/hip_runtime.h>
#include <hip/hip_bf16.h>

// Problem constants (from reference)
#define NU 100000
#define NI 50000
#define NE 1000000
#define NP 500000
// D_IN = D_HID = 128, D_OUT = 64

typedef unsigned short u16;
typedef unsigned int u32;
typedef __attribute__((ext_vector_type(8))) short short8;   // 8 bf16 (4 VGPRs)
typedef __attribute__((ext_vector_type(4))) float f32x4;

static __device__ __forceinline__ u16 f2bf(float f) {
    union { float f; u32 u; } x; x.f = f;
    u32 r = x.u + 0x7fff + ((x.u >> 16) & 1);   // round-to-nearest-even
    return (u16)(r >> 16);
}
static __device__ __forceinline__ float bf2f(u16 h) {
    union { u32 u; float f; } x; x.u = ((u32)h) << 16;
    return x.f;
}

// NOTE (r15 lesson): all feature tables are LINEAR [N][128]/[N][64] bf16.
// Dim-sliced layouts (32B rows) regressed 2.3x: random gathers must keep
// row granularity >= cache line.
// NOTE (r17 lesson): conv TM=32 regressed vs TM=64 (+26us): occupancy wasn't
// the conv bottleneck; halving the tile doubles per-block weight traffic.

// ---------------- fused prep: cvt(h_user) + cvt(h_item) + wtrans + hist ----
// hist2's 2M device-scope atomics are memory-side-bound (r14/r17: 83us,
// VALUBusy 0.6%, WRITE 70MB write-through) — the CUs are idle, so the
// independent cvt/wtrans work rides along in the same launch for free.
// Block ranges: [0,6250) cvt_u | [6250,9375) cvt_i | [9375,9759) wtrans
// | [9759,9759+2*3907) hist (dir = range half). Ranks stored as u16.
#define CVT_U_BLKS 6250              // NU*16/256
#define CVT_I_BLKS 3125              // NI*16/256
#define WT_BLKS 384                  // 768 x-cols / 2 per block
#define HIST_BLKS 3907               // (NE+255)/256
__global__ __launch_bounds__(256) void prep_kernel(
    const float* __restrict__ h_user, u16* __restrict__ hu0b,
    const float* __restrict__ h_item, u16* __restrict__ hi0b,
    const float* __restrict__ Wn01, const float* __restrict__ Ws01,
    const float* __restrict__ Wn2, const float* __restrict__ Ws2,
    u16* __restrict__ wt,
    const int* __restrict__ d0, int* __restrict__ deg0, u16* __restrict__ rank0,
    const int* __restrict__ d1, int* __restrict__ deg1, u16* __restrict__ rank1) {
    int b = blockIdx.x;
    if (b < CVT_U_BLKS + CVT_I_BLKS) {
        const float* in; u16* out;
        int i;
        if (b < CVT_U_BLKS) { in = h_user; out = hu0b; i = b * 256 + threadIdx.x; }
        else { in = h_item; out = hi0b; i = (b - CVT_U_BLKS) * 256 + threadIdx.x; }
        float4 a = ((const float4*)in)[2 * i];
        float4 c = ((const float4*)in)[2 * i + 1];
        ushort4 lo = {f2bf(a.x), f2bf(a.y), f2bf(a.z), f2bf(a.w)};
        ushort4 hi = {f2bf(c.x), f2bf(c.y), f2bf(c.z), f2bf(c.w)};
        ((ushort4*)out)[2 * i]     = lo;
        ((ushort4*)out)[2 * i + 1] = hi;
        return;
    }
    b -= CVT_U_BLKS + CVT_I_BLKS;
    if (b < WT_BLKS) {
        int x = b * 2 + (threadIdx.x >> 7);    // 0..767
        int k = threadIdx.x & 127;
        if (x < 512) {
            int m = x >> 7, n = x & 127;
            const float* Wn = Wn01 + m * 16384;
            const float* Ws = Ws01 + m * 16384;
            size_t o = (size_t)m * 128 * 256;
            wt[o + (size_t)n * 256 + k]       = f2bf(Wn[(size_t)k * 128 + n]);
            wt[o + (size_t)n * 256 + 128 + k] = f2bf(Ws[(size_t)k * 128 + n]);
        } else {
            int m = (x - 512) >> 7;    // 0 = pu, 1 = pi
            int n = (x - 512) & 127;
            size_t o = 131072 + (size_t)m * 16384;
            float v;
            if (m == 0) v = (n < 64) ? Wn2[(size_t)k * 64 + n]
                                     : Ws2[8192 + (size_t)k * 64 + (n - 64)];
            else        v = (n < 64) ? Wn2[8192 + (size_t)k * 64 + n]
                                     : Ws2[(size_t)k * 64 + (n - 64)];
            wt[o + (size_t)n * 128 + k] = f2bf(v);
        }
        return;
    }
    b -= WT_BLKS;
    int dir = (b >= HIST_BLKS);
    int e = (b - dir * HIST_BLKS) * 256 + threadIdx.x;
    if (e >= NE) return;
    if (dir == 0) {
        int d = __builtin_nontemporal_load(&d0[e]);
        int r = atomicAdd(&deg0[d], 1);
        __builtin_nontemporal_store((u16)r, &rank0[e]);
    } else {
        int d = __builtin_nontemporal_load(&d1[e]);
        int r = atomicAdd(&deg1[d], 1);
        __builtin_nontemporal_store((u16)r, &rank1[e]);
    }
}

// ---------------- scans (merged over directions via y) ----------------
__global__ void scan2_local_kernel(const int* __restrict__ in0, int* __restrict__ out0,
                                   int* __restrict__ bsum0, int n0,
                                   const int* __restrict__ in1, int* __restrict__ out1,
                                   int* __restrict__ bsum1, int n1) {
    const int* in; int *out, *bsum; int n;
    if (blockIdx.y == 0) { in = in0; out = out0; bsum = bsum0; n = n0; }
    else                 { in = in1; out = out1; bsum = bsum1; n = n1; }
    __shared__ int s[1024];
    int i = blockIdx.x * 1024 + threadIdx.x;
    int v = (i < n) ? in[i] : 0;
    s[threadIdx.x] = v;
    __syncthreads();
    for (int off = 1; off < 1024; off <<= 1) {
        int t = (threadIdx.x >= off) ? s[threadIdx.x - off] : 0;
        __syncthreads();
        s[threadIdx.x] += t;
        __syncthreads();
    }
    if (i < n) out[i] = s[threadIdx.x] - v;   // exclusive within block
    if (threadIdx.x == 1023) bsum[blockIdx.x] = s[1023];
}

__global__ void scan2_bsum_kernel(int* b0, int nb0, int* b1, int nb1) {
    int* bsum; int nb;
    if (blockIdx.y == 0) { bsum = b0; nb = nb0; }
    else                 { bsum = b1; nb = nb1; }
    __shared__ int s[1024];
    int v = ((int)threadIdx.x < nb) ? bsum[threadIdx.x] : 0;
    s[threadIdx.x] = v;
    __syncthreads();
    for (int off = 1; off < 1024; off <<= 1) {
        int t = (threadIdx.x >= off) ? s[threadIdx.x - off] : 0;
        __syncthreads();
        s[threadIdx.x] += t;
        __syncthreads();
    }
    if ((int)threadIdx.x < nb) bsum[threadIdx.x] = s[threadIdx.x] - v;  // exclusive
}

__global__ void scan2_finalize_kernel(int* __restrict__ rs0, const int* __restrict__ b0,
                                      int n0, int* __restrict__ rs1,
                                      const int* __restrict__ b1, int n1, int E) {
    int* rs; const int* bsum; int n;
    if (blockIdx.y == 0) { rs = rs0; bsum = b0; n = n0; }
    else                 { rs = rs1; bsum = b1; n = n1; }
    int i = blockIdx.x * 1024 + threadIdx.x;
    if (i < n) rs[i] += bsum[blockIdx.x];
    if (i == 0) rs[n] = E;
}

// single-pass atomic-free fill: csr[rs[d] + rank[e]] = src[e].  (u16 ranks)
__global__ void fill2_kernel(const int* __restrict__ s0, const int* __restrict__ d0,
                             const u16* __restrict__ r0, const int* __restrict__ rs0,
                             int* __restrict__ csr0,
                             const int* __restrict__ s1, const int* __restrict__ d1,
                             const u16* __restrict__ r1, const int* __restrict__ rs1,
                             int* __restrict__ csr1, int E) {
    const int *src, *dst, *rs; const u16* rk; int* csr;
    if (blockIdx.y == 0) { src = s0; dst = d0; rk = r0; rs = rs0; csr = csr0; }
    else                 { src = s1; dst = d1; rk = r1; rs = rs1; csr = csr1; }
    int e = blockIdx.x * blockDim.x + threadIdx.x;
    if (e >= E) return;
    int d = __builtin_nontemporal_load(&dst[e]);
    int r = (int)__builtin_nontemporal_load(&rk[e]);
    int s = __builtin_nontemporal_load(&src[e]);
    csr[rs[d] + r] = s;
}

// ---------------- mean aggregation, items + users in ONE launch ----------------
// 16 lanes own one node (8 dims/lane = full 128-dim row); 8-deep edge unroll
// (LLC-latency-bound: FETCH 206MB @ 2.75 TB/s effective; deeper MLP, not BW).
__global__ __launch_bounds__(256) void agg2_kernel(
    const u16* __restrict__ hu, const u16* __restrict__ hi,
    const int* __restrict__ rs_i, const int* __restrict__ csr_i,
    u16* __restrict__ out_i, int gi2,
    const int* __restrict__ rs_u, const int* __restrict__ csr_u,
    u16* __restrict__ out_u) {
    const u16* hsrc; const int *rs, *csr; u16* out; int T, t;
    int bx = blockIdx.x;
    int grp = threadIdx.x >> 4;        // 0..15 node groups per block
    int lr  = threadIdx.x & 15;        // dims lr*8 .. lr*8+7
    if (bx < gi2) { hsrc = hu; rs = rs_i; csr = csr_i; out = out_i; T = NI;
                    t = bx * 16 + grp; }
    else          { hsrc = hi; rs = rs_u; csr = csr_u; out = out_u; T = NU;
                    t = (bx - gi2) * 16 + grp; }
    if (t >= T) return;
    int e0 = rs[t], e1 = rs[t + 1];
    float acc[8] = {};
    int e = e0;
    for (; e + 7 < e1; e += 8) {       // 8 gathers in flight per group
        int s0 = __builtin_nontemporal_load(&csr[e]);
        int s1 = __builtin_nontemporal_load(&csr[e + 1]);
        int s2 = __builtin_nontemporal_load(&csr[e + 2]);
        int s3 = __builtin_nontemporal_load(&csr[e + 3]);
        int s4 = __builtin_nontemporal_load(&csr[e + 4]);
        int s5 = __builtin_nontemporal_load(&csr[e + 5]);
        int s6 = __builtin_nontemporal_load(&csr[e + 6]);
        int s7 = __builtin_nontemporal_load(&csr[e + 7]);
        short8 v0 = *(const short8*)&hsrc[(size_t)s0 * 128 + (lr << 3)];
        short8 v1 = *(const short8*)&hsrc[(size_t)s1 * 128 + (lr << 3)];
        short8 v2 = *(const short8*)&hsrc[(size_t)s2 * 128 + (lr << 3)];
        short8 v3 = *(const short8*)&hsrc[(size_t)s3 * 128 + (lr << 3)];
        short8 v4 = *(const short8*)&hsrc[(size_t)s4 * 128 + (lr << 3)];
        short8 v5 = *(const short8*)&hsrc[(size_t)s5 * 128 + (lr << 3)];
        short8 v6 = *(const short8*)&hsrc[(size_t)s6 * 128 + (lr << 3)];
        short8 v7 = *(const short8*)&hsrc[(size_t)s7 * 128 + (lr << 3)];
        #pragma unroll
        for (int q = 0; q < 8; ++q)
            acc[q] += ((bf2f((u16)v0[q]) + bf2f((u16)v1[q])) +
                       (bf2f((u16)v2[q]) + bf2f((u16)v3[q]))) +
                      ((bf2f((u16)v4[q]) + bf2f((u16)v5[q])) +
                       (bf2f((u16)v6[q]) + bf2f((u16)v7[q])));
    }
    for (; e + 3 < e1; e += 4) {
        int s0 = __builtin_nontemporal_load(&csr[e]);
        int s1 = __builtin_nontemporal_load(&csr[e + 1]);
        int s2 = __builtin_nontemporal_load(&csr[e + 2]);
        int s3 = __builtin_nontemporal_load(&csr[e + 3]);
        short8 v0 = *(const short8*)&hsrc[(size_t)s0 * 128 + (lr << 3)];
        short8 v1 = *(const short8*)&hsrc[(size_t)s1 * 128 + (lr << 3)];
        short8 v2 = *(const short8*)&hsrc[(size_t)s2 * 128 + (lr << 3)];
        short8 v3 = *(const short8*)&hsrc[(size_t)s3 * 128 + (lr << 3)];
        #pragma unroll
        for (int q = 0; q < 8; ++q)
            acc[q] += (bf2f((u16)v0[q]) + bf2f((u16)v1[q])) +
                      (bf2f((u16)v2[q]) + bf2f((u16)v3[q]));
    }
    for (; e < e1; ++e) {
        int s0 = __builtin_nontemporal_load(&csr[e]);
        short8 v0 = *(const short8*)&hsrc[(size_t)s0 * 128 + (lr << 3)];
        #pragma unroll
        for (int q = 0; q < 8; ++q) acc[q] += bf2f((u16)v0[q]);
    }
    float inv = (e1 > e0) ? 1.f / (float)(e1 - e0) : 0.f;
    short8 o;
    #pragma unroll
    for (int q = 0; q < 8; ++q) o[q] = (short)f2bf(acc[q] * inv);
    __builtin_nontemporal_store(o, (short8*)&out[(size_t)t * 128 + (lr << 3)]);
}

// ---------------- layer-2: 64-dim aggregation over projected tables ----------------
// Gathers only cols 0..63 (first 128B) of the [*,128] projected rows.
__global__ __launch_bounds__(256) void agg64_kernel(
    const u16* __restrict__ pu, const u16* __restrict__ pi,
    const int* __restrict__ rs_i, const int* __restrict__ csr_i,
    u16* __restrict__ out_i, int gi64,
    const int* __restrict__ rs_u, const int* __restrict__ csr_u,
    u16* __restrict__ out_u) {
    const u16* hsrc; const int *rs, *csr; u16* out; int T, t;
    int bx = blockIdx.x;
    int grp = threadIdx.x >> 3;        // 0..31 node groups per block
    int lr  = threadIdx.x & 7;         // dims lr*8 .. lr*8+7
    if (bx < gi64) { hsrc = pu; rs = rs_i; csr = csr_i; out = out_i; T = NI;
                     t = bx * 32 + grp; }
    else           { hsrc = pi; rs = rs_u; csr = csr_u; out = out_u; T = NU;
                     t = (bx - gi64) * 32 + grp; }
    if (t >= T) return;
    int e0 = rs[t], e1 = rs[t + 1];
    float acc[8] = {};
    int e = e0;
    for (; e + 7 < e1; e += 8) {
        int s0 = __builtin_nontemporal_load(&csr[e]);
        int s1 = __builtin_nontemporal_load(&csr[e + 1]);
        int s2 = __builtin_nontemporal_load(&csr[e + 2]);
        int s3 = __builtin_nontemporal_load(&csr[e + 3]);
        int s4 = __builtin_nontemporal_load(&csr[e + 4]);
        int s5 = __builtin_nontemporal_load(&csr[e + 5]);
        int s6 = __builtin_nontemporal_load(&csr[e + 6]);
        int s7 = __builtin_nontemporal_load(&csr[e + 7]);
        short8 v0 = *(const short8*)&hsrc[(size_t)s0 * 128 + (lr << 3)];
        short8 v1 = *(const short8*)&hsrc[(size_t)s1 * 128 + (lr << 3)];
        short8 v2 = *(const short8*)&hsrc[(size_t)s2 * 128 + (lr << 3)];
        short8 v3 = *(const short8*)&hsrc[(size_t)s3 * 128 + (lr << 3)];
        short8 v4 = *(const short8*)&hsrc[(size_t)s4 * 128 + (lr << 3)];
        short8 v5 = *(const short8*)&hsrc[(size_t)s5 * 128 + (lr << 3)];
        short8 v6 = *(const short8*)&hsrc[(size_t)s6 * 128 + (lr << 3)];
        short8 v7 = *(const short8*)&hsrc[(size_t)s7 * 128 + (lr << 3)];
        #pragma unroll
        for (int q = 0; q < 8; ++q)
            acc[q] += ((bf2f((u16)v0[q]) + bf2f((u16)v1[q])) +
                       (bf2f((u16)v2[q]) + bf2f((u16)v3[q]))) +
                      ((bf2f((u16)v4[q]) + bf2f((u16)v5[q])) +
                       (bf2f((u16)v6[q]) + bf2f((u16)v7[q])));
    }
    for (; e + 3 < e1; e += 4) {
        int s0 = __builtin_nontemporal_load(&csr[e]);
        int s1 = __builtin_nontemporal_load(&csr[e + 1]);
        int s2 = __builtin_nontemporal_load(&csr[e + 2]);
        int s3 = __builtin_nontemporal_load(&csr[e + 3]);
        short8 v0 = *(const short8*)&hsrc[(size_t)s0 * 128 + (lr << 3)];
        short8 v1 = *(const short8*)&hsrc[(size_t)s1 * 128 + (lr << 3)];
        short8 v2 = *(const short8*)&hsrc[(size_t)s2 * 128 + (lr << 3)];
        short8 v3 = *(const short8*)&hsrc[(size_t)s3 * 128 + (lr << 3)];
        #pragma unroll
        for (int q = 0; q < 8; ++q)
            acc[q] += (bf2f((u16)v0[q]) + bf2f((u16)v1[q])) +
                      (bf2f((u16)v2[q]) + bf2f((u16)v3[q]));
    }
    for (; e < e1; ++e) {
        int s0 = __builtin_nontemporal_load(&csr[e]);
        short8 v0 = *(const short8*)&hsrc[(size_t)s0 * 128 + (lr << 3)];
        #pragma unroll
        for (int q = 0; q < 8; ++q) acc[q] += bf2f((u16)v0[q]);
    }
    float inv = (e1 > e0) ? 1.f / (float)(e1 - e0) : 0.f;
    short8 o;
    #pragma unroll
    for (int q = 0; q < 8; ++q) o[q] = (short)f2bf(acc[q] * inv);
    __builtin_nontemporal_store(o, (short8*)&out[(size_t)t * 64 + (lr << 3)]);
}

// ---------------- conv via MFMA (layers 0/1), items + users in ONE launch ----
// z = [hn|hd] @ Wt^T + bn + bs; relu; row L2-norm. 4 waves, 64-row tile (r14).
__global__ __launch_bounds__(256) void conv2_kernel(
    const u16* __restrict__ hn_i, const u16* __restrict__ hd_i,
    const u16* __restrict__ wt_i, const float* __restrict__ bn_i,
    const float* __restrict__ bs_i, u16* __restrict__ outb_i, int ci,
    const u16* __restrict__ hn_u, const u16* __restrict__ hd_u,
    const u16* __restrict__ wt_u, const float* __restrict__ bn_u,
    const float* __restrict__ bs_u, u16* __restrict__ outb_u)
{
    constexpr int NF   = 2;
    constexpr int FSTR = 132;
    __shared__ u16 smA[64 * 264];                  // 33792 B, reused as f32 out
    __shared__ float psum[4][64];
    __shared__ float sinv[64];
    float* smF = (float*)smA;

    const u16 *hn, *hd, *Wt; const float *bn, *bs; u16* outb; int T, t0;
    if ((int)blockIdx.x < ci) {
        hn = hn_i; hd = hd_i; Wt = wt_i; bn = bn_i; bs = bs_i;
        outb = outb_i; T = NI; t0 = blockIdx.x * 64;
    } else {
        hn = hn_u; hd = hd_u; Wt = wt_u; bn = bn_u; bs = bs_u;
        outb = outb_u; T = NU; t0 = (blockIdx.x - ci) * 64;
    }

    const int tid  = threadIdx.x;
    const int wave = tid >> 6;
    const int lane = tid & 63;
    const int lr   = lane & 15;
    const int lg   = lane >> 4;

    #pragma unroll
    for (int i = 0; i < 8; ++i) {
        int lin = i * 256 + tid;
        int row = lin >> 5;
        int q   = lin & 31;
        int t   = t0 + row; if (t >= T) t = T - 1;
        const u16* srcp = (q < 16) ? &hn[(size_t)t * 128 + (q << 3)]
                                   : &hd[(size_t)t * 128 + ((q - 16) << 3)];
        *(short8*)&smA[row * 264 + (q << 3)] = *(const short8*)srcp;
    }
    __syncthreads();

    const u16* wp[NF];
    float bias[NF];
    #pragma unroll
    for (int ni = 0; ni < NF; ++ni) {
        int col = wave * 32 + ni * 16 + lr;
        wp[ni] = Wt + (size_t)col * 256;
        bias[ni] = bn[col] + bs[col];
    }

    f32x4 acc[4][NF];
    #pragma unroll
    for (int mi = 0; mi < 4; ++mi)
        #pragma unroll
        for (int ni = 0; ni < NF; ++ni)
            acc[mi][ni] = (f32x4){0.f, 0.f, 0.f, 0.f};

    #pragma unroll
    for (int ks = 0; ks < 8; ++ks) {
        const int kb = ks * 32 + (lg << 3);
        short8 b[NF];
        #pragma unroll
        for (int ni = 0; ni < NF; ++ni) b[ni] = *(const short8*)&wp[ni][kb];
        #pragma unroll
        for (int mi = 0; mi < 4; ++mi) {
            short8 a = *(const short8*)&smA[(mi * 16 + lr) * 264 + kb];
            #pragma unroll
            for (int ni = 0; ni < NF; ++ni)
                acc[mi][ni] = __builtin_amdgcn_mfma_f32_16x16x32_bf16(a, b[ni], acc[mi][ni], 0, 0, 0);
        }
    }
    __syncthreads();

    float rsum[4][4];
    #pragma unroll
    for (int mi = 0; mi < 4; ++mi) {
        #pragma unroll
        for (int j = 0; j < 4; ++j) {
            int rowg = mi * 16 + lg * 4 + j;
            float s = 0.f;
            #pragma unroll
            for (int ni = 0; ni < NF; ++ni) {
                float z = fmaxf(acc[mi][ni][j] + bias[ni], 0.f);
                int colg = wave * 32 + ni * 16 + lr;
                smF[rowg * FSTR + colg] = z;
                s = fmaf(z, z, s);
            }
            rsum[mi][j] = s;
        }
    }
    #pragma unroll
    for (int m = 1; m < 16; m <<= 1)
        #pragma unroll
        for (int mi = 0; mi < 4; ++mi)
            #pragma unroll
            for (int j = 0; j < 4; ++j)
                rsum[mi][j] += __shfl_xor(rsum[mi][j], m);
    if (lr == 0) {
        #pragma unroll
        for (int mi = 0; mi < 4; ++mi)
            #pragma unroll
            for (int j = 0; j < 4; ++j)
                psum[wave][mi * 16 + lg * 4 + j] = rsum[mi][j];
    }
    __syncthreads();
    if (tid < 64) {
        float n2 = psum[0][tid] + psum[1][tid] + psum[2][tid] + psum[3][tid];
        sinv[tid] = 1.f / fmaxf(sqrtf(n2), 1e-12f);
    }
    __syncthreads();

    #pragma unroll
    for (int i = 0; i < 4; ++i) {
        int lin = i * 256 + tid;
        int row = lin >> 4, g = lin & 15;
        int t = t0 + row;
        if (t < T) {
            float inv = sinv[row];
            float4 z0 = *(float4*)&smF[row * FSTR + g * 8];
            float4 z1 = *(float4*)&smF[row * FSTR + g * 8 + 4];
            short8 ob = {(short)f2bf(z0.x * inv), (short)f2bf(z0.y * inv),
                         (short)f2bf(z0.z * inv), (short)f2bf(z0.w * inv),
                         (short)f2bf(z1.x * inv), (short)f2bf(z1.y * inv),
                         (short)f2bf(z1.z * inv), (short)f2bf(z1.w * inv)};
            *(short8*)&outb[(size_t)t * 128 + g * 8] = ob;
        }
    }
}

// ---------------- layer-2 pre-projection GEMM: p = h @ [Wn|Ws] (128->128) ----
// No bias/relu/norm. 64-row tile (r14).
__global__ __launch_bounds__(256) void proj2_kernel(
    const u16* __restrict__ A_i, const u16* __restrict__ wt_pi,
    u16* __restrict__ out_i, int ci,
    const u16* __restrict__ A_u, const u16* __restrict__ wt_pu,
    u16* __restrict__ out_u)
{
    constexpr int NF = 2;
    constexpr int FSTR = 132;
    __shared__ float smF[64 * FSTR];               // 33792 B; low half doubles as A
    u16* smA = (u16*)smF;                          // 64 x 136 u16

    const u16 *A, *Wt; u16* outb; int T, t0;
    if ((int)blockIdx.x < ci) {
        A = A_i; Wt = wt_pi; outb = out_i; T = NI; t0 = blockIdx.x * 64;
    } else {
        A = A_u; Wt = wt_pu; outb = out_u; T = NU; t0 = (blockIdx.x - ci) * 64;
    }

    const int tid  = threadIdx.x;
    const int wave = tid >> 6;
    const int lane = tid & 63;
    const int lr   = lane & 15;
    const int lg   = lane >> 4;

    #pragma unroll
    for (int i = 0; i < 4; ++i) {
        int lin = i * 256 + tid;
        int row = lin >> 4;
        int q   = lin & 15;
        int t   = t0 + row; if (t >= T) t = T - 1;
        *(short8*)&smA[row * 136 + (q << 3)] =
            *(const short8*)&A[(size_t)t * 128 + (q << 3)];
    }
    __syncthreads();

    const u16* wp[NF];
    #pragma unroll
    for (int ni = 0; ni < NF; ++ni) {
        int col = wave * 32 + ni * 16 + lr;
        wp[ni] = Wt + (size_t)col * 128;
    }

    f32x4 acc[4][NF];
    #pragma unroll
    for (int mi = 0; mi < 4; ++mi)
        #pragma unroll
        for (int ni = 0; ni < NF; ++ni)
            acc[mi][ni] = (f32x4){0.f, 0.f, 0.f, 0.f};

    #pragma unroll
    for (int ks = 0; ks < 4; ++ks) {
        const int kb = ks * 32 + (lg << 3);
        short8 b[NF];
        #pragma unroll
        for (int ni = 0; ni < NF; ++ni) b[ni] = *(const short8*)&wp[ni][kb];
        #pragma unroll
        for (int mi = 0; mi < 4; ++mi) {
            short8 a = *(const short8*)&smA[(mi * 16 + lr) * 136 + kb];
            #pragma unroll
            for (int ni = 0; ni < NF; ++ni)
                acc[mi][ni] = __builtin_amdgcn_mfma_f32_16x16x32_bf16(a, b[ni], acc[mi][ni], 0, 0, 0);
        }
    }
    __syncthreads();

    #pragma unroll
    for (int mi = 0; mi < 4; ++mi)
        #pragma unroll
        for (int j = 0; j < 4; ++j) {
            int rowg = mi * 16 + lg * 4 + j;
            #pragma unroll
            for (int ni = 0; ni < NF; ++ni)
                smF[rowg * FSTR + wave * 32 + ni * 16 + lr] = acc[mi][ni][j];
        }
    __syncthreads();

    #pragma unroll
    for (int i = 0; i < 4; ++i) {
        int lin = i * 256 + tid;
        int row = lin >> 4, g = lin & 15;
        int t = t0 + row;
        if (t < T) {
            float4 z0 = *(float4*)&smF[row * FSTR + g * 8];
            float4 z1 = *(float4*)&smF[row * FSTR + g * 8 + 4];
            short8 ob = {(short)f2bf(z0.x), (short)f2bf(z0.y),
                         (short)f2bf(z0.z), (short)f2bf(z0.w),
                         (short)f2bf(z1.x), (short)f2bf(z1.y),
                         (short)f2bf(z1.z), (short)f2bf(z1.w)};
            *(short8*)&outb[(size_t)t * 128 + g * 8] = ob;
        }
    }
}

// ---------------- layer-2 combine: z = agg64 + self + biases; relu; L2-norm ----
__global__ __launch_bounds__(256) void combine2_kernel(
    const u16* __restrict__ agg_i, const u16* __restrict__ proj_i,
    const float* __restrict__ bn2, const float* __restrict__ bs2,
    float* __restrict__ outf_i, u16* __restrict__ outb_i, int cbi,
    const u16* __restrict__ agg_u, const u16* __restrict__ proj_u,
    float* __restrict__ outf_u, u16* __restrict__ outb_u)
{
    const u16 *agg, *proj; const float *bn, *bs; float* outf; u16* outb; int T, r0;
    if ((int)blockIdx.x < cbi) {
        agg = agg_i; proj = proj_i; bn = bn2;      bs = bs2;
        outf = outf_i; outb = outb_i; T = NI; r0 = blockIdx.x * 32;
    } else {
        agg = agg_u; proj = proj_u; bn = bn2 + 64; bs = bs2 + 64;
        outf = outf_u; outb = outb_u; T = NU; r0 = (blockIdx.x - cbi) * 32;
    }
    int g = threadIdx.x >> 3, l = threadIdx.x & 7;
    int r = r0 + g;
    if (r >= T) return;
    short8 va = *(const short8*)&agg[(size_t)r * 64 + (l << 3)];
    short8 vs = *(const short8*)&proj[(size_t)r * 128 + 64 + (l << 3)];
    float z[8];
    float s = 0.f;
    #pragma unroll
    for (int q = 0; q < 8; ++q) {
        float v = bf2f((u16)va[q]) + bf2f((u16)vs[q]) + bn[l * 8 + q] + bs[l * 8 + q];
        v = fmaxf(v, 0.f);
        z[q] = v;
        s = fmaf(v, v, s);
    }
    s += __shfl_xor(s, 1);
    s += __shfl_xor(s, 2);
    s += __shfl_xor(s, 4);
    float inv = 1.f / fmaxf(sqrtf(s), 1e-12f);
    short8 ob;
    float4 o0, o1;
    o0.x = z[0] * inv; o0.y = z[1] * inv; o0.z = z[2] * inv; o0.w = z[3] * inv;
    o1.x = z[4] * inv; o1.y = z[5] * inv; o1.z = z[6] * inv; o1.w = z[7] * inv;
    #pragma unroll
    for (int q = 0; q < 8; ++q) ob[q] = (short)f2bf(z[q] * inv);
    *(short8*)&outb[(size_t)r * 64 + (l << 3)] = ob;
    *(float4*)&outf[(size_t)r * 64 + (l << 3)]     = o0;
    *(float4*)&outf[(size_t)r * 64 + (l << 3) + 4] = o1;
}

// ---------------- cosine scores, pos + neg in ONE launch ----------------
__global__ __launch_bounds__(256) void score2_kernel(
    const u16* __restrict__ hu, const u16* __restrict__ hi,
    const int* __restrict__ pu0, const int* __restrict__ pi0, float* __restrict__ out0,
    const int* __restrict__ pu1, const int* __restrict__ pi1, float* __restrict__ out1,
    int P) {
    const int *pu, *pi; float* out;
    if (blockIdx.y == 0) { pu = pu0; pi = pi0; out = out0; }
    else                 { pu = pu1; pi = pi1; out = out1; }
    int g = threadIdx.x >> 3, l = threadIdx.x & 7;
    int p = blockIdx.x * 32 + g;
    if (p >= P) return;
    int u = __builtin_nontemporal_load(&pu[p]);
    int it = __builtin_nontemporal_load(&pi[p]);
    short8 a = *(const short8*)&hu[(size_t)u * 64 + (l << 3)];
    short8 b = *(const short8*)&hi[(size_t)it * 64 + (l << 3)];
    float d = 0.f, na = 0.f, nb = 0.f;
    #pragma unroll
    for (int q = 0; q < 8; ++q) {
        float x = bf2f((u16)a[q]), y = bf2f((u16)b[q]);
        d  = fmaf(x, y, d);
        na = fmaf(x, x, na);
        nb = fmaf(y, y, nb);
    }
    #pragma unroll
    for (int m = 1; m < 8; m <<= 1) {
        d  += __shfl_xor(d, m);
        na += __shfl_xor(na, m);
        nb += __shfl_xor(nb, m);
    }
    if (l == 0) out[p] = d / (fmaxf(sqrtf(na), 1e-12f) * fmaxf(sqrtf(nb), 1e-12f));
}

// ---------------- host ----------------

extern "C" void kernel_launch(void* const* d_in, const int* in_sizes, int n_in,
                              void* d_out, int out_size, void* d_ws, size_t ws_size,
                              hipStream_t stream) {
    const float* h_user = (const float*)d_in[0];
    const float* h_item = (const float*)d_in[1];
    const float* Wn01   = (const float*)d_in[2];
    const float* bn01   = (const float*)d_in[3];
    const float* Ws01   = (const float*)d_in[4];
    const float* bs01   = (const float*)d_in[5];
    const float* Wn2    = (const float*)d_in[6];
    const float* bn2    = (const float*)d_in[7];
    const float* Ws2    = (const float*)d_in[8];
    const float* bs2    = (const float*)d_in[9];
    const int* u2i_src  = (const int*)d_in[10];
    const int* u2i_dst  = (const int*)d_in[11];
    const int* i2u_src  = (const int*)d_in[12];
    const int* i2u_dst  = (const int*)d_in[13];
    const int* pos_u    = (const int*)d_in[14];
    const int* pos_i    = (const int*)d_in[15];
    const int* neg_u    = (const int*)d_in[16];
    const int* neg_i    = (const int*)d_in[17];

    float* out = (float*)d_out;
    float* out_hu = out;                       // [NU,64]
    float* out_hi = out + (size_t)NU * 64;     // [NI,64]
    float* out_pos = out + (size_t)NU * 64 + (size_t)NI * 64;
    float* out_neg = out_pos + NP;

    // workspace layout
    char* ws = (char*)d_ws;
    size_t off = 0;
    auto alloc = [&](size_t bytes) -> void* {
        void* p = ws + off;
        off = (off + bytes + 255) & ~(size_t)255;
        return p;
    };
    u16* hu0b = (u16*)alloc((size_t)NU * 128 * 2);   // bf16 copies of inputs
    u16* hi0b = (u16*)alloc((size_t)NI * 128 * 2);
    u16* hu_b = (u16*)alloc((size_t)NU * 128 * 2);   // layer-0 out; layer-2 proj_u reuse
    u16* hi_b = (u16*)alloc((size_t)NI * 128 * 2);   // layer-0 out; layer-2 proj_i reuse
    u16* hu_a = (u16*)alloc((size_t)NU * 128 * 2);   // layer-1 out
    u16* hi_a = (u16*)alloc((size_t)NI * 128 * 2);
    u16* agg_i = (u16*)alloc((size_t)NI * 128 * 2);  // agg outputs (bf16)
    u16* agg_u = (u16*)alloc((size_t)NU * 128 * 2);
    u16* hu2b = (u16*)alloc((size_t)NU * 64 * 2);    // final embeddings (bf16, scores)
    u16* hi2b = (u16*)alloc((size_t)NI * 64 * 2);
    u16* wt_all = (u16*)alloc((size_t)(4 * 128 * 256 + 2 * 128 * 128) * 2);
    u16* wt_l0_i = wt_all;                 // each 128x256
    u16* wt_l0_u = wt_all + 32768;
    u16* wt_l1_i = wt_all + 65536;
    u16* wt_l1_u = wt_all + 98304;
    u16* wt_pu   = wt_all + 131072;        // 128x128 [Wn2_i | Ws2_u]
    u16* wt_pi   = wt_all + 147456;        // 128x128 [Wn2_u | Ws2_i]
    int* csr_u2i = (int*)alloc((size_t)NE * 4);
    int* csr_i2u = (int*)alloc((size_t)NE * 4);
    int* rs_i   = (int*)alloc((size_t)(NI + 1) * 4);
    int* rs_u   = (int*)alloc((size_t)(NU + 1) * 4);
    int* deg    = (int*)alloc((size_t)(NI + NU) * 4);   // deg_i | deg_u
    int* bsum_i = (int*)alloc(1024 * 4);
    int* bsum_u = (int*)alloc(1024 * 4);
    int* deg_i = deg, *deg_u = deg + NI;
    // u16 rank arrays alias the (not-yet-live) agg buffers (prep/fill2
    // complete before the first agg2 writes them; single stream = sequential).
    u16* rank_i = agg_i;
    u16* rank_u = agg_u;
    // layer-2: proj buffers reuse the dead layer-0 outputs; agg64 reuses agg bufs
    u16* proj_u = hu_b;
    u16* proj_i = hi_b;
    u16* agg64_i = agg_i;
    u16* agg64_u = agg_u;
    (void)ws_size; (void)in_sizes; (void)n_in; (void)out_size;

    const int eblocks = (NE + 255) / 256;   // 3907 == HIST_BLKS

    // ---- fused prep: cvt x2 + wtrans + hist (ranks) ----
    hipMemsetAsync(deg, 0, (size_t)(NI + NU) * 4, stream);
    prep_kernel<<<CVT_U_BLKS + CVT_I_BLKS + WT_BLKS + 2 * HIST_BLKS, 256, 0, stream>>>(
        h_user, hu0b, h_item, hi0b, Wn01, Ws01, Wn2, Ws2, wt_all,
        u2i_dst, deg_i, rank_i, i2u_dst, deg_u, rank_u);

    const int nb_i = (NI + 1023) / 1024, nb_u = (NU + 1023) / 1024;
    const int nb_max = (nb_i > nb_u) ? nb_i : nb_u;
    scan2_local_kernel<<<dim3(nb_max, 2), 1024, 0, stream>>>(
        deg_i, rs_i, bsum_i, NI, deg_u, rs_u, bsum_u, NU);
    scan2_bsum_kernel<<<dim3(1, 2), 1024, 0, stream>>>(bsum_i, nb_i, bsum_u, nb_u);
    scan2_finalize_kernel<<<dim3(nb_max, 2), 1024, 0, stream>>>(
        rs_i, bsum_i, NI, rs_u, bsum_u, NU, NE);
    fill2_kernel<<<dim3(eblocks, 2), 256, 0, stream>>>(
        u2i_src, u2i_dst, rank_i, rs_i, csr_u2i,
        i2u_src, i2u_dst, rank_u, rs_u, csr_i2u, NE);

    const int gi2 = (NI + 15) / 16, gu2 = (NU + 15) / 16;    // agg2 sub-grids
    const int gi64 = (NI + 31) / 32, gu64 = (NU + 31) / 32;  // agg64 sub-grids
    const int ci = (NI + 63) / 64, cu = (NU + 63) / 64;      // conv/proj sub-grids
    const int cbi = (NI + 31) / 32, cbu = (NU + 31) / 32;    // combine sub-grids

    // ---- layer 0 ----
    agg2_kernel<<<gi2 + gu2, 256, 0, stream>>>(hu0b, hi0b, rs_i, csr_u2i, agg_i, gi2,
                                               rs_u, csr_i2u, agg_u);
    conv2_kernel<<<ci + cu, 256, 0, stream>>>(
        agg_i, hi0b, wt_l0_i, bn01 + 0, bs01 + 0, hi_b, ci,
        agg_u, hu0b, wt_l0_u, bn01 + 128, bs01 + 128, hu_b);
    // ---- layer 1 ----
    agg2_kernel<<<gi2 + gu2, 256, 0, stream>>>(hu_b, hi_b, rs_i, csr_u2i, agg_i, gi2,
                                               rs_u, csr_i2u, agg_u);
    conv2_kernel<<<ci + cu, 256, 0, stream>>>(
        agg_i, hi_b, wt_l1_i, bn01 + 256, bs01 + 256, hi_a, ci,
        agg_u, hu_b, wt_l1_u, bn01 + 384, bs01 + 384, hu_a);
    // ---- layer 2: pre-project (mean(h)@W = mean(h@W)), 64-dim agg, combine ----
    proj2_kernel<<<ci + cu, 256, 0, stream>>>(hi_a, wt_pi, proj_i, ci,
                                              hu_a, wt_pu, proj_u);
    agg64_kernel<<<gi64 + gu64, 256, 0, stream>>>(proj_u, proj_i, rs_i, csr_u2i,
                                                  agg64_i, gi64,
                                                  rs_u, csr_i2u, agg64_u);
    combine2_kernel<<<cbi + cbu, 256, 0, stream>>>(
        agg64_i, proj_i, bn2, bs2, out_hi, hi2b, cbi,
        agg64_u, proj_u, out_hu, hu2b);

    // ---- cosine scores (pos + neg in one launch) ----
    score2_kernel<<<dim3((NP + 31) / 32, 2), 256, 0, stream>>>(
        hu2b, hi2b, pos_u, pos_i, out_pos, neg_u, neg_i, out_neg, NP);
}

// Round 19
// 479.237 us; speedup vs baseline: 1.6770x; 1.0275x over previous
//
#include <hip/hip_runtime.h>
#include <hip/hip_bf16.h>

// Problem constants (from reference)
#define NU 100000
#define NI 50000
#define NE 1000000
#define NP 500000
// D_IN = D_HID = 128, D_OUT = 64

typedef unsigned short u16;
typedef unsigned int u32;
typedef __attribute__((ext_vector_type(8))) short short8;   // 8 bf16 (4 VGPRs)
typedef __attribute__((ext_vector_type(4))) float f32x4;

static __device__ __forceinline__ u16 f2bf(float f) {
    union { float f; u32 u; } x; x.f = f;
    u32 r = x.u + 0x7fff + ((x.u >> 16) & 1);   // round-to-nearest-even
    return (u16)(r >> 16);
}
static __device__ __forceinline__ float bf2f(u16 h) {
    union { u32 u; float f; } x; x.u = ((u32)h) << 16;
    return x.f;
}

// NOTE (r15): feature tables stay LINEAR — dim-slicing (sub-line rows) lost 2.3x.
// NOTE (r17): conv TM=32 lost vs TM=64 (+26us) — occupancy wasn't conv's limit.
// NOTE (r18): contiguous role ranges in a fused kernel DON'T overlap — the
// grid drains in dispatch order. Roles must be interleaved (this round).

// ---------------- fused prep: hist (atomics) interleaved with cvt + wtrans ----
// hist's 2M device-scope atomics are latency/write-through-bound with idle
// CUs (r14: 83us, VALUBusy 0.6%). Interleaving roles block-by-block makes the
// streaming cvt/wtrans work co-resident with the atomic waves.
#define CVT_U_BLKS 6250              // NU*16/256
#define CVT_I_BLKS 3125              // NI*16/256
#define WT_BLKS 384                  // 768 x-cols / 2 per block
#define HIST_BLKS 3907               // (NE+255)/256 per direction
#define H_TOT (2 * HIST_BLKS)        // 7814
#define OTH_TOT (CVT_U_BLKS + CVT_I_BLKS + WT_BLKS)   // 9759
__global__ __launch_bounds__(256) void prep_kernel(
    const float* __restrict__ h_user, u16* __restrict__ hu0b,
    const float* __restrict__ h_item, u16* __restrict__ hi0b,
    const float* __restrict__ Wn01, const float* __restrict__ Ws01,
    const float* __restrict__ Wn2, const float* __restrict__ Ws2,
    u16* __restrict__ wt,
    const int* __restrict__ d0, int* __restrict__ deg0, u16* __restrict__ rank0,
    const int* __restrict__ d1, int* __restrict__ deg1, u16* __restrict__ rank1) {
    int b = blockIdx.x;
    bool is_hist; int idx;
    if (b < 2 * H_TOT) { is_hist = !(b & 1); idx = b >> 1; }
    else               { is_hist = false;    idx = H_TOT + (b - 2 * H_TOT); }

    if (is_hist) {
        int dir = (idx >= HIST_BLKS);
        int e = (idx - dir * HIST_BLKS) * 256 + threadIdx.x;
        if (e >= NE) return;
        if (dir == 0) {
            int d = __builtin_nontemporal_load(&d0[e]);
            int r = atomicAdd(&deg0[d], 1);
            __builtin_nontemporal_store((u16)r, &rank0[e]);
        } else {
            int d = __builtin_nontemporal_load(&d1[e]);
            int r = atomicAdd(&deg1[d], 1);
            __builtin_nontemporal_store((u16)r, &rank1[e]);
        }
        return;
    }

    if (idx < CVT_U_BLKS + CVT_I_BLKS) {
        const float* in; u16* out;
        int i;
        if (idx < CVT_U_BLKS) { in = h_user; out = hu0b; i = idx * 256 + threadIdx.x; }
        else { in = h_item; out = hi0b; i = (idx - CVT_U_BLKS) * 256 + threadIdx.x; }
        float4 a = ((const float4*)in)[2 * i];
        float4 c = ((const float4*)in)[2 * i + 1];
        ushort4 lo = {f2bf(a.x), f2bf(a.y), f2bf(a.z), f2bf(a.w)};
        ushort4 hi = {f2bf(c.x), f2bf(c.y), f2bf(c.z), f2bf(c.w)};
        ((ushort4*)out)[2 * i]     = lo;
        ((ushort4*)out)[2 * i + 1] = hi;
        return;
    }
    idx -= CVT_U_BLKS + CVT_I_BLKS;
    {
        int x = idx * 2 + (threadIdx.x >> 7);    // 0..767
        int k = threadIdx.x & 127;
        if (x < 512) {
            int m = x >> 7, n = x & 127;
            const float* Wn = Wn01 + m * 16384;
            const float* Ws = Ws01 + m * 16384;
            size_t o = (size_t)m * 128 * 256;
            wt[o + (size_t)n * 256 + k]       = f2bf(Wn[(size_t)k * 128 + n]);
            wt[o + (size_t)n * 256 + 128 + k] = f2bf(Ws[(size_t)k * 128 + n]);
        } else {
            int m = (x - 512) >> 7;    // 0 = pu, 1 = pi
            int n = (x - 512) & 127;
            size_t o = 131072 + (size_t)m * 16384;
            float v;
            if (m == 0) v = (n < 64) ? Wn2[(size_t)k * 64 + n]
                                     : Ws2[8192 + (size_t)k * 64 + (n - 64)];
            else        v = (n < 64) ? Wn2[8192 + (size_t)k * 64 + n]
                                     : Ws2[(size_t)k * 64 + (n - 64)];
            wt[o + (size_t)n * 128 + k] = f2bf(v);
        }
    }
}

// ---------------- scans (merged over directions via y) ----------------
__global__ void scan2_local_kernel(const int* __restrict__ in0, int* __restrict__ out0,
                                   int* __restrict__ bsum0, int n0,
                                   const int* __restrict__ in1, int* __restrict__ out1,
                                   int* __restrict__ bsum1, int n1) {
    const int* in; int *out, *bsum; int n;
    if (blockIdx.y == 0) { in = in0; out = out0; bsum = bsum0; n = n0; }
    else                 { in = in1; out = out1; bsum = bsum1; n = n1; }
    __shared__ int s[1024];
    int i = blockIdx.x * 1024 + threadIdx.x;
    int v = (i < n) ? in[i] : 0;
    s[threadIdx.x] = v;
    __syncthreads();
    for (int off = 1; off < 1024; off <<= 1) {
        int t = (threadIdx.x >= off) ? s[threadIdx.x - off] : 0;
        __syncthreads();
        s[threadIdx.x] += t;
        __syncthreads();
    }
    if (i < n) out[i] = s[threadIdx.x] - v;   // exclusive within block
    if (threadIdx.x == 1023) bsum[blockIdx.x] = s[1023];
}

__global__ void scan2_bsum_kernel(int* b0, int nb0, int* b1, int nb1) {
    int* bsum; int nb;
    if (blockIdx.y == 0) { bsum = b0; nb = nb0; }
    else                 { bsum = b1; nb = nb1; }
    __shared__ int s[1024];
    int v = ((int)threadIdx.x < nb) ? bsum[threadIdx.x] : 0;
    s[threadIdx.x] = v;
    __syncthreads();
    for (int off = 1; off < 1024; off <<= 1) {
        int t = (threadIdx.x >= off) ? s[threadIdx.x - off] : 0;
        __syncthreads();
        s[threadIdx.x] += t;
        __syncthreads();
    }
    if ((int)threadIdx.x < nb) bsum[threadIdx.x] = s[threadIdx.x] - v;  // exclusive
}

__global__ void scan2_finalize_kernel(int* __restrict__ rs0, const int* __restrict__ b0,
                                      int n0, int* __restrict__ rs1,
                                      const int* __restrict__ b1, int n1, int E) {
    int* rs; const int* bsum; int n;
    if (blockIdx.y == 0) { rs = rs0; bsum = b0; n = n0; }
    else                 { rs = rs1; bsum = b1; n = n1; }
    int i = blockIdx.x * 1024 + threadIdx.x;
    if (i < n) rs[i] += bsum[blockIdx.x];
    if (i == 0) rs[n] = E;
}

// single-pass atomic-free fill: csr[rs[d] + rank[e]] = src[e].  (u16 ranks)
__global__ void fill2_kernel(const int* __restrict__ s0, const int* __restrict__ d0,
                             const u16* __restrict__ r0, const int* __restrict__ rs0,
                             int* __restrict__ csr0,
                             const int* __restrict__ s1, const int* __restrict__ d1,
                             const u16* __restrict__ r1, const int* __restrict__ rs1,
                             int* __restrict__ csr1, int E) {
    const int *src, *dst, *rs; const u16* rk; int* csr;
    if (blockIdx.y == 0) { src = s0; dst = d0; rk = r0; rs = rs0; csr = csr0; }
    else                 { src = s1; dst = d1; rk = r1; rs = rs1; csr = csr1; }
    int e = blockIdx.x * blockDim.x + threadIdx.x;
    if (e >= E) return;
    int d = __builtin_nontemporal_load(&dst[e]);
    int r = (int)__builtin_nontemporal_load(&rk[e]);
    int s = __builtin_nontemporal_load(&src[e]);
    csr[rs[d] + r] = s;
}

// ---------------- mean aggregation, items + users in ONE launch ----------------
// 16 lanes own one node (8 dims/lane = full 128-dim row); 8-deep edge unroll.
// At the LLC random-gather floor (FETCH ~206MB = 8-XCD-replicated tables).
__global__ __launch_bounds__(256) void agg2_kernel(
    const u16* __restrict__ hu, const u16* __restrict__ hi,
    const int* __restrict__ rs_i, const int* __restrict__ csr_i,
    u16* __restrict__ out_i, int gi2,
    const int* __restrict__ rs_u, const int* __restrict__ csr_u,
    u16* __restrict__ out_u) {
    const u16* hsrc; const int *rs, *csr; u16* out; int T, t;
    int bx = blockIdx.x;
    int grp = threadIdx.x >> 4;        // 0..15 node groups per block
    int lr  = threadIdx.x & 15;        // dims lr*8 .. lr*8+7
    if (bx < gi2) { hsrc = hu; rs = rs_i; csr = csr_i; out = out_i; T = NI;
                    t = bx * 16 + grp; }
    else          { hsrc = hi; rs = rs_u; csr = csr_u; out = out_u; T = NU;
                    t = (bx - gi2) * 16 + grp; }
    if (t >= T) return;
    int e0 = rs[t], e1 = rs[t + 1];
    float acc[8] = {};
    int e = e0;
    for (; e + 7 < e1; e += 8) {       // 8 gathers in flight per group
        int s0 = __builtin_nontemporal_load(&csr[e]);
        int s1 = __builtin_nontemporal_load(&csr[e + 1]);
        int s2 = __builtin_nontemporal_load(&csr[e + 2]);
        int s3 = __builtin_nontemporal_load(&csr[e + 3]);
        int s4 = __builtin_nontemporal_load(&csr[e + 4]);
        int s5 = __builtin_nontemporal_load(&csr[e + 5]);
        int s6 = __builtin_nontemporal_load(&csr[e + 6]);
        int s7 = __builtin_nontemporal_load(&csr[e + 7]);
        short8 v0 = *(const short8*)&hsrc[(size_t)s0 * 128 + (lr << 3)];
        short8 v1 = *(const short8*)&hsrc[(size_t)s1 * 128 + (lr << 3)];
        short8 v2 = *(const short8*)&hsrc[(size_t)s2 * 128 + (lr << 3)];
        short8 v3 = *(const short8*)&hsrc[(size_t)s3 * 128 + (lr << 3)];
        short8 v4 = *(const short8*)&hsrc[(size_t)s4 * 128 + (lr << 3)];
        short8 v5 = *(const short8*)&hsrc[(size_t)s5 * 128 + (lr << 3)];
        short8 v6 = *(const short8*)&hsrc[(size_t)s6 * 128 + (lr << 3)];
        short8 v7 = *(const short8*)&hsrc[(size_t)s7 * 128 + (lr << 3)];
        #pragma unroll
        for (int q = 0; q < 8; ++q)
            acc[q] += ((bf2f((u16)v0[q]) + bf2f((u16)v1[q])) +
                       (bf2f((u16)v2[q]) + bf2f((u16)v3[q]))) +
                      ((bf2f((u16)v4[q]) + bf2f((u16)v5[q])) +
                       (bf2f((u16)v6[q]) + bf2f((u16)v7[q])));
    }
    for (; e + 3 < e1; e += 4) {
        int s0 = __builtin_nontemporal_load(&csr[e]);
        int s1 = __builtin_nontemporal_load(&csr[e + 1]);
        int s2 = __builtin_nontemporal_load(&csr[e + 2]);
        int s3 = __builtin_nontemporal_load(&csr[e + 3]);
        short8 v0 = *(const short8*)&hsrc[(size_t)s0 * 128 + (lr << 3)];
        short8 v1 = *(const short8*)&hsrc[(size_t)s1 * 128 + (lr << 3)];
        short8 v2 = *(const short8*)&hsrc[(size_t)s2 * 128 + (lr << 3)];
        short8 v3 = *(const short8*)&hsrc[(size_t)s3 * 128 + (lr << 3)];
        #pragma unroll
        for (int q = 0; q < 8; ++q)
            acc[q] += (bf2f((u16)v0[q]) + bf2f((u16)v1[q])) +
                      (bf2f((u16)v2[q]) + bf2f((u16)v3[q]));
    }
    for (; e < e1; ++e) {
        int s0 = __builtin_nontemporal_load(&csr[e]);
        short8 v0 = *(const short8*)&hsrc[(size_t)s0 * 128 + (lr << 3)];
        #pragma unroll
        for (int q = 0; q < 8; ++q) acc[q] += bf2f((u16)v0[q]);
    }
    float inv = (e1 > e0) ? 1.f / (float)(e1 - e0) : 0.f;
    short8 o;
    #pragma unroll
    for (int q = 0; q < 8; ++q) o[q] = (short)f2bf(acc[q] * inv);
    __builtin_nontemporal_store(o, (short8*)&out[(size_t)t * 128 + (lr << 3)]);
}

// ---------------- layer-2: 64-dim aggregation over projected tables ----------------
__global__ __launch_bounds__(256) void agg64_kernel(
    const u16* __restrict__ pu, const u16* __restrict__ pi,
    const int* __restrict__ rs_i, const int* __restrict__ csr_i,
    u16* __restrict__ out_i, int gi64,
    const int* __restrict__ rs_u, const int* __restrict__ csr_u,
    u16* __restrict__ out_u) {
    const u16* hsrc; const int *rs, *csr; u16* out; int T, t;
    int bx = blockIdx.x;
    int grp = threadIdx.x >> 3;        // 0..31 node groups per block
    int lr  = threadIdx.x & 7;         // dims lr*8 .. lr*8+7
    if (bx < gi64) { hsrc = pu; rs = rs_i; csr = csr_i; out = out_i; T = NI;
                     t = bx * 32 + grp; }
    else           { hsrc = pi; rs = rs_u; csr = csr_u; out = out_u; T = NU;
                     t = (bx - gi64) * 32 + grp; }
    if (t >= T) return;
    int e0 = rs[t], e1 = rs[t + 1];
    float acc[8] = {};
    int e = e0;
    for (; e + 7 < e1; e += 8) {
        int s0 = __builtin_nontemporal_load(&csr[e]);
        int s1 = __builtin_nontemporal_load(&csr[e + 1]);
        int s2 = __builtin_nontemporal_load(&csr[e + 2]);
        int s3 = __builtin_nontemporal_load(&csr[e + 3]);
        int s4 = __builtin_nontemporal_load(&csr[e + 4]);
        int s5 = __builtin_nontemporal_load(&csr[e + 5]);
        int s6 = __builtin_nontemporal_load(&csr[e + 6]);
        int s7 = __builtin_nontemporal_load(&csr[e + 7]);
        short8 v0 = *(const short8*)&hsrc[(size_t)s0 * 128 + (lr << 3)];
        short8 v1 = *(const short8*)&hsrc[(size_t)s1 * 128 + (lr << 3)];
        short8 v2 = *(const short8*)&hsrc[(size_t)s2 * 128 + (lr << 3)];
        short8 v3 = *(const short8*)&hsrc[(size_t)s3 * 128 + (lr << 3)];
        short8 v4 = *(const short8*)&hsrc[(size_t)s4 * 128 + (lr << 3)];
        short8 v5 = *(const short8*)&hsrc[(size_t)s5 * 128 + (lr << 3)];
        short8 v6 = *(const short8*)&hsrc[(size_t)s6 * 128 + (lr << 3)];
        short8 v7 = *(const short8*)&hsrc[(size_t)s7 * 128 + (lr << 3)];
        #pragma unroll
        for (int q = 0; q < 8; ++q)
            acc[q] += ((bf2f((u16)v0[q]) + bf2f((u16)v1[q])) +
                       (bf2f((u16)v2[q]) + bf2f((u16)v3[q]))) +
                      ((bf2f((u16)v4[q]) + bf2f((u16)v5[q])) +
                       (bf2f((u16)v6[q]) + bf2f((u16)v7[q])));
    }
    for (; e + 3 < e1; e += 4) {
        int s0 = __builtin_nontemporal_load(&csr[e]);
        int s1 = __builtin_nontemporal_load(&csr[e + 1]);
        int s2 = __builtin_nontemporal_load(&csr[e + 2]);
        int s3 = __builtin_nontemporal_load(&csr[e + 3]);
        short8 v0 = *(const short8*)&hsrc[(size_t)s0 * 128 + (lr << 3)];
        short8 v1 = *(const short8*)&hsrc[(size_t)s1 * 128 + (lr << 3)];
        short8 v2 = *(const short8*)&hsrc[(size_t)s2 * 128 + (lr << 3)];
        short8 v3 = *(const short8*)&hsrc[(size_t)s3 * 128 + (lr << 3)];
        #pragma unroll
        for (int q = 0; q < 8; ++q)
            acc[q] += (bf2f((u16)v0[q]) + bf2f((u16)v1[q])) +
                      (bf2f((u16)v2[q]) + bf2f((u16)v3[q]));
    }
    for (; e < e1; ++e) {
        int s0 = __builtin_nontemporal_load(&csr[e]);
        short8 v0 = *(const short8*)&hsrc[(size_t)s0 * 128 + (lr << 3)];
        #pragma unroll
        for (int q = 0; q < 8; ++q) acc[q] += bf2f((u16)v0[q]);
    }
    float inv = (e1 > e0) ? 1.f / (float)(e1 - e0) : 0.f;
    short8 o;
    #pragma unroll
    for (int q = 0; q < 8; ++q) o[q] = (short)f2bf(acc[q] * inv);
    __builtin_nontemporal_store(o, (short8*)&out[(size_t)t * 64 + (lr << 3)]);
}

// ---------------- conv via MFMA (layers 0/1), items + users in ONE launch ----
// z = [hn|hd] @ Wt^T + bn + bs; relu; row L2-norm. 4 waves, 64-row tile (r14).
__global__ __launch_bounds__(256) void conv2_kernel(
    const u16* __restrict__ hn_i, const u16* __restrict__ hd_i,
    const u16* __restrict__ wt_i, const float* __restrict__ bn_i,
    const float* __restrict__ bs_i, u16* __restrict__ outb_i, int ci,
    const u16* __restrict__ hn_u, const u16* __restrict__ hd_u,
    const u16* __restrict__ wt_u, const float* __restrict__ bn_u,
    const float* __restrict__ bs_u, u16* __restrict__ outb_u)
{
    constexpr int NF   = 2;
    constexpr int FSTR = 132;
    __shared__ u16 smA[64 * 264];                  // 33792 B, reused as f32 out
    __shared__ float psum[4][64];
    __shared__ float sinv[64];
    float* smF = (float*)smA;

    const u16 *hn, *hd, *Wt; const float *bn, *bs; u16* outb; int T, t0;
    if ((int)blockIdx.x < ci) {
        hn = hn_i; hd = hd_i; Wt = wt_i; bn = bn_i; bs = bs_i;
        outb = outb_i; T = NI; t0 = blockIdx.x * 64;
    } else {
        hn = hn_u; hd = hd_u; Wt = wt_u; bn = bn_u; bs = bs_u;
        outb = outb_u; T = NU; t0 = (blockIdx.x - ci) * 64;
    }

    const int tid  = threadIdx.x;
    const int wave = tid >> 6;
    const int lane = tid & 63;
    const int lr   = lane & 15;
    const int lg   = lane >> 4;

    #pragma unroll
    for (int i = 0; i < 8; ++i) {
        int lin = i * 256 + tid;
        int row = lin >> 5;
        int q   = lin & 31;
        int t   = t0 + row; if (t >= T) t = T - 1;
        const u16* srcp = (q < 16) ? &hn[(size_t)t * 128 + (q << 3)]
                                   : &hd[(size_t)t * 128 + ((q - 16) << 3)];
        *(short8*)&smA[row * 264 + (q << 3)] = *(const short8*)srcp;
    }
    __syncthreads();

    const u16* wp[NF];
    float bias[NF];
    #pragma unroll
    for (int ni = 0; ni < NF; ++ni) {
        int col = wave * 32 + ni * 16 + lr;
        wp[ni] = Wt + (size_t)col * 256;
        bias[ni] = bn[col] + bs[col];
    }

    f32x4 acc[4][NF];
    #pragma unroll
    for (int mi = 0; mi < 4; ++mi)
        #pragma unroll
        for (int ni = 0; ni < NF; ++ni)
            acc[mi][ni] = (f32x4){0.f, 0.f, 0.f, 0.f};

    #pragma unroll
    for (int ks = 0; ks < 8; ++ks) {
        const int kb = ks * 32 + (lg << 3);
        short8 b[NF];
        #pragma unroll
        for (int ni = 0; ni < NF; ++ni) b[ni] = *(const short8*)&wp[ni][kb];
        #pragma unroll
        for (int mi = 0; mi < 4; ++mi) {
            short8 a = *(const short8*)&smA[(mi * 16 + lr) * 264 + kb];
            #pragma unroll
            for (int ni = 0; ni < NF; ++ni)
                acc[mi][ni] = __builtin_amdgcn_mfma_f32_16x16x32_bf16(a, b[ni], acc[mi][ni], 0, 0, 0);
        }
    }
    __syncthreads();

    float rsum[4][4];
    #pragma unroll
    for (int mi = 0; mi < 4; ++mi) {
        #pragma unroll
        for (int j = 0; j < 4; ++j) {
            int rowg = mi * 16 + lg * 4 + j;
            float s = 0.f;
            #pragma unroll
            for (int ni = 0; ni < NF; ++ni) {
                float z = fmaxf(acc[mi][ni][j] + bias[ni], 0.f);
                int colg = wave * 32 + ni * 16 + lr;
                smF[rowg * FSTR + colg] = z;
                s = fmaf(z, z, s);
            }
            rsum[mi][j] = s;
        }
    }
    #pragma unroll
    for (int m = 1; m < 16; m <<= 1)
        #pragma unroll
        for (int mi = 0; mi < 4; ++mi)
            #pragma unroll
            for (int j = 0; j < 4; ++j)
                rsum[mi][j] += __shfl_xor(rsum[mi][j], m);
    if (lr == 0) {
        #pragma unroll
        for (int mi = 0; mi < 4; ++mi)
            #pragma unroll
            for (int j = 0; j < 4; ++j)
                psum[wave][mi * 16 + lg * 4 + j] = rsum[mi][j];
    }
    __syncthreads();
    if (tid < 64) {
        float n2 = psum[0][tid] + psum[1][tid] + psum[2][tid] + psum[3][tid];
        sinv[tid] = 1.f / fmaxf(sqrtf(n2), 1e-12f);
    }
    __syncthreads();

    #pragma unroll
    for (int i = 0; i < 4; ++i) {
        int lin = i * 256 + tid;
        int row = lin >> 4, g = lin & 15;
        int t = t0 + row;
        if (t < T) {
            float inv = sinv[row];
            float4 z0 = *(float4*)&smF[row * FSTR + g * 8];
            float4 z1 = *(float4*)&smF[row * FSTR + g * 8 + 4];
            short8 ob = {(short)f2bf(z0.x * inv), (short)f2bf(z0.y * inv),
                         (short)f2bf(z0.z * inv), (short)f2bf(z0.w * inv),
                         (short)f2bf(z1.x * inv), (short)f2bf(z1.y * inv),
                         (short)f2bf(z1.z * inv), (short)f2bf(z1.w * inv)};
            *(short8*)&outb[(size_t)t * 128 + g * 8] = ob;
        }
    }
}

// ---------------- layer-2 pre-projection GEMM: p = h @ [Wn|Ws] (128->128) ----
__global__ __launch_bounds__(256) void proj2_kernel(
    const u16* __restrict__ A_i, const u16* __restrict__ wt_pi,
    u16* __restrict__ out_i, int ci,
    const u16* __restrict__ A_u, const u16* __restrict__ wt_pu,
    u16* __restrict__ out_u)
{
    constexpr int NF = 2;
    constexpr int FSTR = 132;
    __shared__ float smF[64 * FSTR];               // 33792 B; low half doubles as A
    u16* smA = (u16*)smF;                          // 64 x 136 u16

    const u16 *A, *Wt; u16* outb; int T, t0;
    if ((int)blockIdx.x < ci) {
        A = A_i; Wt = wt_pi; outb = out_i; T = NI; t0 = blockIdx.x * 64;
    } else {
        A = A_u; Wt = wt_pu; outb = out_u; T = NU; t0 = (blockIdx.x - ci) * 64;
    }

    const int tid  = threadIdx.x;
    const int wave = tid >> 6;
    const int lane = tid & 63;
    const int lr   = lane & 15;
    const int lg   = lane >> 4;

    #pragma unroll
    for (int i = 0; i < 4; ++i) {
        int lin = i * 256 + tid;
        int row = lin >> 4;
        int q   = lin & 15;
        int t   = t0 + row; if (t >= T) t = T - 1;
        *(short8*)&smA[row * 136 + (q << 3)] =
            *(const short8*)&A[(size_t)t * 128 + (q << 3)];
    }
    __syncthreads();

    const u16* wp[NF];
    #pragma unroll
    for (int ni = 0; ni < NF; ++ni) {
        int col = wave * 32 + ni * 16 + lr;
        wp[ni] = Wt + (size_t)col * 128;
    }

    f32x4 acc[4][NF];
    #pragma unroll
    for (int mi = 0; mi < 4; ++mi)
        #pragma unroll
        for (int ni = 0; ni < NF; ++ni)
            acc[mi][ni] = (f32x4){0.f, 0.f, 0.f, 0.f};

    #pragma unroll
    for (int ks = 0; ks < 4; ++ks) {
        const int kb = ks * 32 + (lg << 3);
        short8 b[NF];
        #pragma unroll
        for (int ni = 0; ni < NF; ++ni) b[ni] = *(const short8*)&wp[ni][kb];
        #pragma unroll
        for (int mi = 0; mi < 4; ++mi) {
            short8 a = *(const short8*)&smA[(mi * 16 + lr) * 136 + kb];
            #pragma unroll
            for (int ni = 0; ni < NF; ++ni)
                acc[mi][ni] = __builtin_amdgcn_mfma_f32_16x16x32_bf16(a, b[ni], acc[mi][ni], 0, 0, 0);
        }
    }
    __syncthreads();

    #pragma unroll
    for (int mi = 0; mi < 4; ++mi)
        #pragma unroll
        for (int j = 0; j < 4; ++j) {
            int rowg = mi * 16 + lg * 4 + j;
            #pragma unroll
            for (int ni = 0; ni < NF; ++ni)
                smF[rowg * FSTR + wave * 32 + ni * 16 + lr] = acc[mi][ni][j];
        }
    __syncthreads();

    #pragma unroll
    for (int i = 0; i < 4; ++i) {
        int lin = i * 256 + tid;
        int row = lin >> 4, g = lin & 15;
        int t = t0 + row;
        if (t < T) {
            float4 z0 = *(float4*)&smF[row * FSTR + g * 8];
            float4 z1 = *(float4*)&smF[row * FSTR + g * 8 + 4];
            short8 ob = {(short)f2bf(z0.x), (short)f2bf(z0.y),
                         (short)f2bf(z0.z), (short)f2bf(z0.w),
                         (short)f2bf(z1.x), (short)f2bf(z1.y),
                         (short)f2bf(z1.z), (short)f2bf(z1.w)};
            *(short8*)&outb[(size_t)t * 128 + g * 8] = ob;
        }
    }
}

// ---------------- layer-2 combine: z = agg64 + self + biases; relu; L2-norm ----
__global__ __launch_bounds__(256) void combine2_kernel(
    const u16* __restrict__ agg_i, const u16* __restrict__ proj_i,
    const float* __restrict__ bn2, const float* __restrict__ bs2,
    float* __restrict__ outf_i, u16* __restrict__ outb_i, int cbi,
    const u16* __restrict__ agg_u, const u16* __restrict__ proj_u,
    float* __restrict__ outf_u, u16* __restrict__ outb_u)
{
    const u16 *agg, *proj; const float *bn, *bs; float* outf; u16* outb; int T, r0;
    if ((int)blockIdx.x < cbi) {
        agg = agg_i; proj = proj_i; bn = bn2;      bs = bs2;
        outf = outf_i; outb = outb_i; T = NI; r0 = blockIdx.x * 32;
    } else {
        agg = agg_u; proj = proj_u; bn = bn2 + 64; bs = bs2 + 64;
        outf = outf_u; outb = outb_u; T = NU; r0 = (blockIdx.x - cbi) * 32;
    }
    int g = threadIdx.x >> 3, l = threadIdx.x & 7;
    int r = r0 + g;
    if (r >= T) return;
    short8 va = *(const short8*)&agg[(size_t)r * 64 + (l << 3)];
    short8 vs = *(const short8*)&proj[(size_t)r * 128 + 64 + (l << 3)];
    float z[8];
    float s = 0.f;
    #pragma unroll
    for (int q = 0; q < 8; ++q) {
        float v = bf2f((u16)va[q]) + bf2f((u16)vs[q]) + bn[l * 8 + q] + bs[l * 8 + q];
        v = fmaxf(v, 0.f);
        z[q] = v;
        s = fmaf(v, v, s);
    }
    s += __shfl_xor(s, 1);
    s += __shfl_xor(s, 2);
    s += __shfl_xor(s, 4);
    float inv = 1.f / fmaxf(sqrtf(s), 1e-12f);
    short8 ob;
    float4 o0, o1;
    o0.x = z[0] * inv; o0.y = z[1] * inv; o0.z = z[2] * inv; o0.w = z[3] * inv;
    o1.x = z[4] * inv; o1.y = z[5] * inv; o1.z = z[6] * inv; o1.w = z[7] * inv;
    #pragma unroll
    for (int q = 0; q < 8; ++q) ob[q] = (short)f2bf(z[q] * inv);
    *(short8*)&outb[(size_t)r * 64 + (l << 3)] = ob;
    *(float4*)&outf[(size_t)r * 64 + (l << 3)]     = o0;
    *(float4*)&outf[(size_t)r * 64 + (l << 3) + 4] = o1;
}

// ---------------- cosine scores, pos + neg in ONE launch ----------------
__global__ __launch_bounds__(256) void score2_kernel(
    const u16* __restrict__ hu, const u16* __restrict__ hi,
    const int* __restrict__ pu0, const int* __restrict__ pi0, float* __restrict__ out0,
    const int* __restrict__ pu1, const int* __restrict__ pi1, float* __restrict__ out1,
    int P) {
    const int *pu, *pi; float* out;
    if (blockIdx.y == 0) { pu = pu0; pi = pi0; out = out0; }
    else                 { pu = pu1; pi = pi1; out = out1; }
    int g = threadIdx.x >> 3, l = threadIdx.x & 7;
    int p = blockIdx.x * 32 + g;
    if (p >= P) return;
    int u = __builtin_nontemporal_load(&pu[p]);
    int it = __builtin_nontemporal_load(&pi[p]);
    short8 a = *(const short8*)&hu[(size_t)u * 64 + (l << 3)];
    short8 b = *(const short8*)&hi[(size_t)it * 64 + (l << 3)];
    float d = 0.f, na = 0.f, nb = 0.f;
    #pragma unroll
    for (int q = 0; q < 8; ++q) {
        float x = bf2f((u16)a[q]), y = bf2f((u16)b[q]);
        d  = fmaf(x, y, d);
        na = fmaf(x, x, na);
        nb = fmaf(y, y, nb);
    }
    #pragma unroll
    for (int m = 1; m < 8; m <<= 1) {
        d  += __shfl_xor(d, m);
        na += __shfl_xor(na, m);
        nb += __shfl_xor(nb, m);
    }
    if (l == 0) out[p] = d / (fmaxf(sqrtf(na), 1e-12f) * fmaxf(sqrtf(nb), 1e-12f));
}

// ---------------- host ----------------

extern "C" void kernel_launch(void* const* d_in, const int* in_sizes, int n_in,
                              void* d_out, int out_size, void* d_ws, size_t ws_size,
                              hipStream_t stream) {
    const float* h_user = (const float*)d_in[0];
    const float* h_item = (const float*)d_in[1];
    const float* Wn01   = (const float*)d_in[2];
    const float* bn01   = (const float*)d_in[3];
    const float* Ws01   = (const float*)d_in[4];
    const float* bs01   = (const float*)d_in[5];
    const float* Wn2    = (const float*)d_in[6];
    const float* bn2    = (const float*)d_in[7];
    const float* Ws2    = (const float*)d_in[8];
    const float* bs2    = (const float*)d_in[9];
    const int* u2i_src  = (const int*)d_in[10];
    const int* u2i_dst  = (const int*)d_in[11];
    const int* i2u_src  = (const int*)d_in[12];
    const int* i2u_dst  = (const int*)d_in[13];
    const int* pos_u    = (const int*)d_in[14];
    const int* pos_i    = (const int*)d_in[15];
    const int* neg_u    = (const int*)d_in[16];
    const int* neg_i    = (const int*)d_in[17];

    float* out = (float*)d_out;
    float* out_hu = out;                       // [NU,64]
    float* out_hi = out + (size_t)NU * 64;     // [NI,64]
    float* out_pos = out + (size_t)NU * 64 + (size_t)NI * 64;
    float* out_neg = out_pos + NP;

    // workspace layout
    char* ws = (char*)d_ws;
    size_t off = 0;
    auto alloc = [&](size_t bytes) -> void* {
        void* p = ws + off;
        off = (off + bytes + 255) & ~(size_t)255;
        return p;
    };
    u16* hu0b = (u16*)alloc((size_t)NU * 128 * 2);   // bf16 copies of inputs
    u16* hi0b = (u16*)alloc((size_t)NI * 128 * 2);
    u16* hu_b = (u16*)alloc((size_t)NU * 128 * 2);   // layer-0 out; layer-2 proj_u reuse
    u16* hi_b = (u16*)alloc((size_t)NI * 128 * 2);   // layer-0 out; layer-2 proj_i reuse
    u16* hu_a = (u16*)alloc((size_t)NU * 128 * 2);   // layer-1 out
    u16* hi_a = (u16*)alloc((size_t)NI * 128 * 2);
    u16* agg_i = (u16*)alloc((size_t)NI * 128 * 2);  // agg outputs (bf16)
    u16* agg_u = (u16*)alloc((size_t)NU * 128 * 2);
    u16* hu2b = (u16*)alloc((size_t)NU * 64 * 2);    // final embeddings (bf16, scores)
    u16* hi2b = (u16*)alloc((size_t)NI * 64 * 2);
    u16* wt_all = (u16*)alloc((size_t)(4 * 128 * 256 + 2 * 128 * 128) * 2);
    u16* wt_l0_i = wt_all;                 // each 128x256
    u16* wt_l0_u = wt_all + 32768;
    u16* wt_l1_i = wt_all + 65536;
    u16* wt_l1_u = wt_all + 98304;
    u16* wt_pu   = wt_all + 131072;        // 128x128 [Wn2_i | Ws2_u]
    u16* wt_pi   = wt_all + 147456;        // 128x128 [Wn2_u | Ws2_i]
    int* csr_u2i = (int*)alloc((size_t)NE * 4);
    int* csr_i2u = (int*)alloc((size_t)NE * 4);
    int* rs_i   = (int*)alloc((size_t)(NI + 1) * 4);
    int* rs_u   = (int*)alloc((size_t)(NU + 1) * 4);
    int* deg    = (int*)alloc((size_t)(NI + NU) * 4);   // deg_i | deg_u
    int* bsum_i = (int*)alloc(1024 * 4);
    int* bsum_u = (int*)alloc(1024 * 4);
    int* deg_i = deg, *deg_u = deg + NI;
    // u16 rank arrays alias the (not-yet-live) agg buffers (prep/fill2
    // complete before the first agg2 writes them; single stream = sequential).
    u16* rank_i = agg_i;
    u16* rank_u = agg_u;
    // layer-2: proj buffers reuse the dead layer-0 outputs; agg64 reuses agg bufs
    u16* proj_u = hu_b;
    u16* proj_i = hi_b;
    u16* agg64_i = agg_i;
    u16* agg64_u = agg_u;
    (void)ws_size; (void)in_sizes; (void)n_in; (void)out_size;

    const int eblocks = (NE + 255) / 256;   // 3907 == HIST_BLKS

    // ---- fused prep: hist interleaved with cvt x2 + wtrans ----
    hipMemsetAsync(deg, 0, (size_t)(NI + NU) * 4, stream);
    prep_kernel<<<H_TOT + OTH_TOT, 256, 0, stream>>>(
        h_user, hu0b, h_item, hi0b, Wn01, Ws01, Wn2, Ws2, wt_all,
        u2i_dst, deg_i, rank_i, i2u_dst, deg_u, rank_u);

    const int nb_i = (NI + 1023) / 1024, nb_u = (NU + 1023) / 1024;
    const int nb_max = (nb_i > nb_u) ? nb_i : nb_u;
    scan2_local_kernel<<<dim3(nb_max, 2), 1024, 0, stream>>>(
        deg_i, rs_i, bsum_i, NI, deg_u, rs_u, bsum_u, NU);
    scan2_bsum_kernel<<<dim3(1, 2), 1024, 0, stream>>>(bsum_i, nb_i, bsum_u, nb_u);
    scan2_finalize_kernel<<<dim3(nb_max, 2), 1024, 0, stream>>>(
        rs_i, bsum_i, NI, rs_u, bsum_u, NU, NE);
    fill2_kernel<<<dim3(eblocks, 2), 256, 0, stream>>>(
        u2i_src, u2i_dst, rank_i, rs_i, csr_u2i,
        i2u_src, i2u_dst, rank_u, rs_u, csr_i2u, NE);

    const int gi2 = (NI + 15) / 16, gu2 = (NU + 15) / 16;    // agg2 sub-grids
    const int gi64 = (NI + 31) / 32, gu64 = (NU + 31) / 32;  // agg64 sub-grids
    const int ci = (NI + 63) / 64, cu = (NU + 63) / 64;      // conv/proj sub-grids
    const int cbi = (NI + 31) / 32, cbu = (NU + 31) / 32;    // combine sub-grids

    // ---- layer 0 ----
    agg2_kernel<<<gi2 + gu2, 256, 0, stream>>>(hu0b, hi0b, rs_i, csr_u2i, agg_i, gi2,
                                               rs_u, csr_i2u, agg_u);
    conv2_kernel<<<ci + cu, 256, 0, stream>>>(
        agg_i, hi0b, wt_l0_i, bn01 + 0, bs01 + 0, hi_b, ci,
        agg_u, hu0b, wt_l0_u, bn01 + 128, bs01 + 128, hu_b);
    // ---- layer 1 ----
    agg2_kernel<<<gi2 + gu2, 256, 0, stream>>>(hu_b, hi_b, rs_i, csr_u2i, agg_i, gi2,
                                               rs_u, csr_i2u, agg_u);
    conv2_kernel<<<ci + cu, 256, 0, stream>>>(
        agg_i, hi_b, wt_l1_i, bn01 + 256, bs01 + 256, hi_a, ci,
        agg_u, hu_b, wt_l1_u, bn01 + 384, bs01 + 384, hu_a);
    // ---- layer 2: pre-project (mean(h)@W = mean(h@W)), 64-dim agg, combine ----
    proj2_kernel<<<ci + cu, 256, 0, stream>>>(hi_a, wt_pi, proj_i, ci,
                                              hu_a, wt_pu, proj_u);
    agg64_kernel<<<gi64 + gu64, 256, 0, stream>>>(proj_u, proj_i, rs_i, csr_u2i,
                                                  agg64_i, gi64,
                                                  rs_u, csr_i2u, agg64_u);
    combine2_kernel<<<cbi + cbu, 256, 0, stream>>>(
        agg64_i, proj_i, bn2, bs2, out_hi, hi2b, cbi,
        agg64_u, proj_u, out_hu, hu2b);

    // ---- cosine scores (pos + neg in one launch) ----
    score2_kernel<<<dim3((NP + 31) / 32, 2), 256, 0, stream>>>(
        hu2b, hi2b, pos_u, pos_i, out_pos, neg_u, neg_i, out_neg, NP);
}